// Round 6
// baseline (516.362 us; speedup 1.0000x reference)
//
#include <hip/hip_runtime.h>
#include <hip/hip_bf16.h>
#include <cstdint>
#include <cstddef>

#define HEADS 8
#define HID 64
#define HF 512              // HEADS*HID
#define NEG_SLOPE 0.2f
#define LN_EPS 1e-5f

typedef __hip_bfloat16 bf16;
typedef __attribute__((ext_vector_type(8))) __bf16 bf16v8;
typedef __attribute__((ext_vector_type(4))) float f32x4;

// ---------------- helpers ---------------------------------------------------
__device__ __forceinline__ float wsum64(float v) {
#pragma unroll
  for (int o = 32; o > 0; o >>= 1) v += __shfl_xor(v, o, 64);
  return v;
}
__device__ __forceinline__ int wsum64i(int v) {
#pragma unroll
  for (int o = 32; o > 0; o >>= 1) v += __shfl_xor(v, o, 64);
  return v;
}
__device__ __forceinline__ float leaky(float v) { return v >= 0.f ? v : NEG_SLOPE * v; }
__device__ __forceinline__ float bits2f(unsigned short u) {
  return __uint_as_float(((unsigned)u) << 16);
}
__device__ __forceinline__ unsigned short f2bits(float x) {
  union { bf16 h; unsigned short u; } bu;
  bu.h = __float2bfloat16(x);
  return bu.u;
}

// ---------------- edge normalize + count (handles int64 or int32) -----------
__global__ __launch_bounds__(256)
void convert_count(const int* __restrict__ ei, int* __restrict__ esrc,
                   int* __restrict__ edst, int* __restrict__ counts, int E) {
  int e = blockIdx.x * 256 + threadIdx.x;
  if (e >= E) return;
  bool i64 = (ei[1] == 0) && (ei[3] == 0) && (ei[5] == 0) && (ei[7] == 0);
  int s, d;
  if (i64) { s = ei[2 * (size_t)e]; d = ei[2 * ((size_t)E + e)]; }
  else     { s = ei[e];             d = ei[E + e]; }
  esrc[e] = s; edst[e] = d;
  atomicAdd(&counts[d], 1);
}

// ---------------- hierarchical exclusive scan over (counts[i]+1) ------------
#define SCAN_T 256
#define SCAN_EPT 4
#define SCAN_CHUNK (SCAN_T * SCAN_EPT)   // 1024

__global__ __launch_bounds__(SCAN_T)
void scan_pass1(const int* __restrict__ counts, int* __restrict__ bsum, int N) {
  int b = blockIdx.x, t = threadIdx.x;
  int base = b * SCAN_CHUNK + t * SCAN_EPT;
  int s = 0;
#pragma unroll
  for (int i = 0; i < SCAN_EPT; ++i) {
    int idx = base + i;
    if (idx < N) s += counts[idx] + 1;
  }
  int lane = t & 63, w = t >> 6;
  int tot = wsum64i(s);
  __shared__ int ws[4];
  if (lane == 0) ws[w] = tot;
  __syncthreads();
  if (t == 0) bsum[b] = ws[0] + ws[1] + ws[2] + ws[3];
}

__global__ __launch_bounds__(64)
void scan_pass2(const int* __restrict__ bsum, int* __restrict__ boff, int NB) {
  int t = threadIdx.x;
  int own = t < NB ? bsum[t] : 0;
  int v = own;
#pragma unroll
  for (int o = 1; o < 64; o <<= 1) {
    int u = __shfl_up(v, o, 64);
    if (t >= o) v += u;
  }
  if (t < NB) boff[t] = v - own;   // exclusive
}

__global__ __launch_bounds__(SCAN_T)
void scan_pass3(const int* __restrict__ counts, const int* __restrict__ boff,
                int* __restrict__ row_ptr, int* __restrict__ cursor, int N, int Etot) {
  int b = blockIdx.x, t = threadIdx.x;
  int base = b * SCAN_CHUNK + t * SCAN_EPT;
  int c[SCAN_EPT];
  int s = 0;
#pragma unroll
  for (int i = 0; i < SCAN_EPT; ++i) {
    int idx = base + i;
    c[i] = idx < N ? counts[idx] + 1 : 0;
    s += c[i];
  }
  int lane = t & 63, w = t >> 6;
  int inc = s;
#pragma unroll
  for (int o = 1; o < 64; o <<= 1) {
    int u = __shfl_up(inc, o, 64);
    if (lane >= o) inc += u;
  }
  __shared__ int wsums[4];
  if (lane == 63) wsums[w] = inc;
  __syncthreads();
  int woff = 0;
  for (int i = 0; i < w; ++i) woff += wsums[i];
  int run = inc - s + woff + boff[b];
#pragma unroll
  for (int i = 0; i < SCAN_EPT; ++i) {
    int idx = base + i;
    if (idx < N) { row_ptr[idx] = run; cursor[idx] = run; run += c[i]; }
  }
  if (b == 0 && t == 0) row_ptr[N] = Etot;
}

__global__ __launch_bounds__(256)
void scatter_kernel(const int* __restrict__ esrc, const int* __restrict__ edst,
                    int* __restrict__ cursor, int* __restrict__ col, int N, int E) {
  int e = blockIdx.x * 256 + threadIdx.x;
  int Etot = E + N;
  if (e >= Etot) return;
  int s = e < E ? esrc[e] : e - E;
  int d = e < E ? edst[e] : e - E;
  int pos = atomicAdd(&cursor[d], 1);
  col[pos] = s;
}

// ---------------- prep: x -> bf16 padded; W -> W^T bf16 padded ---------------
__global__ __launch_bounds__(256)
void convert_pad_x(const float* __restrict__ x, bf16* __restrict__ xbf,
                   int M, int K, int Kp) {
  int idx = blockIdx.x * 256 + threadIdx.x;
  if (idx >= M * Kp) return;
  int row = idx / Kp, colk = idx - row * Kp;
  float v = colk < K ? x[(size_t)row * K + colk] : 0.f;
  xbf[idx] = __float2bfloat16(v);
}

__global__ __launch_bounds__(256)
void transpose_w(const float* __restrict__ W, bf16* __restrict__ Wt,
                 int K, int Ncols, int Kp) {
  int idx = blockIdx.x * 256 + threadIdx.x;
  if (idx >= Ncols * Kp) return;
  int n = idx / Kp, k = idx - n * Kp;
  float v = k < K ? W[(size_t)k * Ncols + n] : 0.f;
  Wt[idx] = __float2bfloat16(v);
}

// ---------------- MFMA GEMM + fused alpha epilogue ---------------------------
// C[M,512] = A[M,K](bf16) @ Bt[512,K](bf16)^T ; also alpha_s/d[M,8] = h . a
// Each wave covers 64 rows x 64 cols = one full head -> complete alpha, no atomics.
#define LDSW 40   // LDS row stride in shorts (32 data + 8 pad, 80B: 16B-aligned)
__global__ __launch_bounds__(256)
void gemm_mfma(const bf16* __restrict__ A, const bf16* __restrict__ Bt,
               bf16* __restrict__ C,
               const float* __restrict__ as_g, const float* __restrict__ ad_g,
               float* __restrict__ alpha_s, float* __restrict__ alpha_d,
               int M, int Ncols, int K) {
  __shared__ short Alds[128 * LDSW];
  __shared__ short Blds[128 * LDSW];
  const int tid = threadIdx.x;
  const int wave = tid >> 6, lane = tid & 63;
  const int wr = wave >> 1, wc = wave & 1;
  const int row0 = blockIdx.x * 128, col0 = blockIdx.y * 128;
  const int lrow = lane & 15;
  const int kc = lane >> 4;
  f32x4 acc[4][4] = {};

  for (int k0 = 0; k0 < K; k0 += 32) {
#pragma unroll
    for (int i = 0; i < 2; ++i) {
      int idx = tid + i * 256;
      int r = idx >> 2, c4 = idx & 3;
      uint4 va = make_uint4(0, 0, 0, 0);
      int gm = row0 + r;
      if (gm < M) va = *reinterpret_cast<const uint4*>(A + (size_t)gm * K + k0 + c4 * 8);
      *reinterpret_cast<uint4*>(&Alds[r * LDSW + c4 * 8]) = va;
      uint4 vb = *reinterpret_cast<const uint4*>(Bt + (size_t)(col0 + r) * K + k0 + c4 * 8);
      *reinterpret_cast<uint4*>(&Blds[r * LDSW + c4 * 8]) = vb;
    }
    __syncthreads();
    bf16v8 af[4], bfr[4];
#pragma unroll
    for (int r = 0; r < 4; ++r)
      af[r] = *reinterpret_cast<const bf16v8*>(&Alds[(wr * 64 + r * 16 + lrow) * LDSW + kc * 8]);
#pragma unroll
    for (int c = 0; c < 4; ++c)
      bfr[c] = *reinterpret_cast<const bf16v8*>(&Blds[(wc * 64 + c * 16 + lrow) * LDSW + kc * 8]);
#pragma unroll
    for (int r = 0; r < 4; ++r)
#pragma unroll
      for (int c = 0; c < 4; ++c)
        acc[r][c] = __builtin_amdgcn_mfma_f32_16x16x32_bf16(af[r], bfr[c], acc[r][c], 0, 0, 0);
    __syncthreads();
  }

  // C write: C/D layout col=lane&15, row=(lane>>4)*4+j  [m89]
  const int crow = (lane >> 4) * 4;
  const int ccol = lane & 15;
#pragma unroll
  for (int r = 0; r < 4; ++r) {
#pragma unroll
    for (int c = 0; c < 4; ++c) {
      int gc = col0 + wc * 64 + c * 16 + ccol;
#pragma unroll
      for (int j = 0; j < 4; ++j) {
        int gr = row0 + wr * 64 + r * 16 + crow + j;
        if (gr < M) C[(size_t)gr * Ncols + gc] = __float2bfloat16(acc[r][c][j]);
      }
    }
  }

  // fused alpha epilogue: this wave's 64 cols = head (col0+wc*64)>>6
  const int head = (col0 + wc * 64) >> 6;
  float asf[4], adf[4];
#pragma unroll
  for (int c = 0; c < 4; ++c) {
    asf[c] = as_g[head * HID + c * 16 + ccol];
    adf[c] = ad_g[head * HID + c * 16 + ccol];
  }
#pragma unroll
  for (int r = 0; r < 4; ++r) {
#pragma unroll
    for (int j = 0; j < 4; ++j) {
      float ps = 0.f, pd = 0.f;
#pragma unroll
      for (int c = 0; c < 4; ++c) {
        ps = fmaf(acc[r][c][j], asf[c], ps);
        pd = fmaf(acc[r][c][j], adf[c], pd);
      }
#pragma unroll
      for (int o = 1; o < 16; o <<= 1) {
        ps += __shfl_xor(ps, o, 64);
        pd += __shfl_xor(pd, o, 64);
      }
      if (ccol == 0) {
        int gr = row0 + wr * 64 + r * 16 + crow + j;
        if (gr < M) {
          alpha_s[gr * HEADS + head] = ps;
          alpha_d[gr * HEADS + head] = pd;
        }
      }
    }
  }
}

// ---------------- fused aggregate (online softmax) + epilogue ---------------
// ONE WAVE per node: lane owns 8 features [8*lane, 8*lane+8), head = lane>>3.
// 4 nodes per 256-thread block. LN via wsum64 (no barrier).
template <int LAYER>
__global__ __launch_bounds__(256)
void aggregate_kernel(const int* __restrict__ row_ptr, const int* __restrict__ col,
                      const bf16* __restrict__ hbuf,
                      const float* __restrict__ alpha_s, const float* __restrict__ alpha_d,
                      const bf16* __restrict__ resid,
                      const float* __restrict__ bias, const float* __restrict__ g,
                      const float* __restrict__ b,
                      bf16* __restrict__ out_bf, int N) {
  int w = threadIdx.x >> 6;
  int lane = threadIdx.x & 63;
  int nn = blockIdx.x * 4 + w;
  bool valid = nn < N;
  int n = valid ? nn : 0;
  int h = lane >> 3;
  float adh = alpha_d[n * HEADS + h];
  float m = -1e30f, den = 0.f;
  float a[8] = {};
  int lo = row_ptr[n], hi = row_ptr[n + 1];

  // prefetched state for edge j
  int sj = col[lo];
  float asj = alpha_s[sj * HEADS + h];
  uint4 u = *reinterpret_cast<const uint4*>(hbuf + (size_t)sj * HF + lane * 8);

  for (int j = lo; j < hi; ++j) {
    float e = leaky(asj + adh);
    uint4 uc = u;
    if (j + 1 < hi) {                      // prefetch next edge
      int sn = col[j + 1];
      asj = alpha_s[sn * HEADS + h];
      u = *reinterpret_cast<const uint4*>(hbuf + (size_t)sn * HF + lane * 8);
    }
    if (e > m) {                           // online-softmax rescale
      float sc = __expf(m - e);
      den *= sc;
#pragma unroll
      for (int i = 0; i < 8; ++i) a[i] *= sc;
      m = e;
    }
    float ex = __expf(e - m);
    den += ex;
    const unsigned short* us = reinterpret_cast<const unsigned short*>(&uc);
#pragma unroll
    for (int i = 0; i < 8; ++i) a[i] = fmaf(ex, bits2f(us[i]), a[i]);
  }
  float inv = 1.f / den;
#pragma unroll
  for (int i = 0; i < 8; ++i) a[i] *= inv;

  if (LAYER < 2) {
    float4 b0 = ((const float4*)bias)[lane * 2];
    float4 b1 = ((const float4*)bias)[lane * 2 + 1];
    a[0] += b0.x; a[1] += b0.y; a[2] += b0.z; a[3] += b0.w;
    a[4] += b1.x; a[5] += b1.y; a[6] += b1.z; a[7] += b1.w;
    if (LAYER == 1) {
      uint4 rr = *reinterpret_cast<const uint4*>(resid + (size_t)n * HF + lane * 8);
      const unsigned short* rs = reinterpret_cast<const unsigned short*>(&rr);
#pragma unroll
      for (int i = 0; i < 8; ++i) a[i] += bits2f(rs[i]);
    }
    float s = 0.f, ss = 0.f;
#pragma unroll
    for (int i = 0; i < 8; ++i) { s += a[i]; ss += a[i] * a[i]; }
    s = wsum64(s); ss = wsum64(ss);
    float mu = s * (1.f / HF);
    float var = ss * (1.f / HF) - mu * mu;
    float rs = rsqrtf(var + LN_EPS);
    float4 g0 = ((const float4*)g)[lane * 2], g1 = ((const float4*)g)[lane * 2 + 1];
    float4 e0 = ((const float4*)b)[lane * 2], e1 = ((const float4*)b)[lane * 2 + 1];
    float gg[8] = {g0.x, g0.y, g0.z, g0.w, g1.x, g1.y, g1.z, g1.w};
    float be[8] = {e0.x, e0.y, e0.z, e0.w, e1.x, e1.y, e1.z, e1.w};
    unsigned short o[8];
#pragma unroll
    for (int i = 0; i < 8; ++i)
      o[i] = f2bits(fmaxf((a[i] - mu) * rs * gg[i] + be[i], 0.f));
    if (valid)
      *reinterpret_cast<uint4*>(out_bf + (size_t)n * HF + lane * 8) =
          *reinterpret_cast<const uint4*>(o);
  } else {
    // head mean via per-wave LDS slab (no cross-wave sync needed)
    __shared__ float lds[4][HF];
#pragma unroll
    for (int i = 0; i < 8; ++i) lds[w][lane * 8 + i] = a[i];
    // same-wave ds_write -> ds_read: compiler inserts lgkmcnt wait
    float v = 0.f;
#pragma unroll
    for (int hh = 0; hh < HEADS; ++hh) v += lds[w][hh * HID + lane];
    v = v * (1.f / HEADS) + bias[lane];
    float s = wsum64(v);
    float ss = wsum64(v * v);
    float mu = s * (1.f / HID);
    float var = ss * (1.f / HID) - mu * mu;
    float rs = rsqrtf(var + LN_EPS);
    v = fmaxf((v - mu) * rs * g[lane] + b[lane], 0.f);
    if (valid) out_bf[(size_t)n * HID + lane] = __float2bfloat16(v);
  }
}

// ---------------- final linear: [N,64]bf16 @ [64,2] + b ---------------------
__global__ __launch_bounds__(256)
void final_linear_kernel(const bf16* __restrict__ D, const float* __restrict__ w,
                         const float* __restrict__ bb, float* __restrict__ out, int N) {
  int wid = (blockIdx.x * 256 + threadIdx.x) >> 6;
  int lane = threadIdx.x & 63;
  if (wid >= N) return;
  float v = __bfloat162float(D[(size_t)wid * HID + lane]);
  float s0 = wsum64(v * w[lane * 2 + 0]);
  float s1 = wsum64(v * w[lane * 2 + 1]);
  if (lane == 0) {
    out[(size_t)wid * 2 + 0] = s0 + bb[0];
    out[(size_t)wid * 2 + 1] = s1 + bb[1];
  }
}

// ===========================================================================
extern "C" void kernel_launch(void* const* d_in, const int* in_sizes, int n_in,
                              void* d_out, int out_size, void* d_ws, size_t ws_size,
                              hipStream_t stream) {
  const float* x  = (const float*)d_in[0];
  const int*   ei = (const int*)d_in[1];
  const int N = in_sizes[0] / 165;       // 50000
  const int E = in_sizes[1] / 2;         // 400000
  const int Etot = E + N;
  const int K0P = 192;

  const float* W[3]  = {(const float*)d_in[2],  (const float*)d_in[8],  (const float*)d_in[14]};
  const float* As[3] = {(const float*)d_in[3],  (const float*)d_in[9],  (const float*)d_in[15]};
  const float* Ad[3] = {(const float*)d_in[4],  (const float*)d_in[10], (const float*)d_in[16]};
  const float* Bi[3] = {(const float*)d_in[5],  (const float*)d_in[11], (const float*)d_in[17]};
  const float* Lg[3] = {(const float*)d_in[6],  (const float*)d_in[12], (const float*)d_in[18]};
  const float* Lb[3] = {(const float*)d_in[7],  (const float*)d_in[13], (const float*)d_in[19]};
  const float* lin_w = (const float*)d_in[20];
  const float* lin_b = (const float*)d_in[21];

  // ---- workspace carve-up ----
  char* p = (char*)d_ws;
  auto alloc = [&](size_t bytes) {
    char* r = p;
    p += (bytes + 255) & ~(size_t)255;
    return r;
  };
  bf16* feat0   = (bf16*)alloc((size_t)N * HF * 2);   // layer outputs; aliases xbf
  bf16* hbuf    = (bf16*)alloc((size_t)N * HF * 2);
  bf16* bufD    = (bf16*)alloc((size_t)N * HID * 2);
  float* alpha_s = (float*)alloc((size_t)N * HEADS * 4);
  float* alpha_d = (float*)alloc((size_t)N * HEADS * 4);
  bf16* W0t = (bf16*)alloc((size_t)HF * K0P * 2);
  bf16* W1t = (bf16*)alloc((size_t)HF * HF * 2);
  bf16* W2t = (bf16*)alloc((size_t)HF * HF * 2);
  int* esrc    = (int*)alloc((size_t)E * 4);
  int* edst    = (int*)alloc((size_t)E * 4);
  int* counts  = (int*)alloc((size_t)N * 4);
  int* row_ptr = (int*)alloc((size_t)(N + 1) * 4);
  int* cursor  = (int*)alloc((size_t)N * 4);
  int* col     = (int*)alloc((size_t)Etot * 4);
  int* bsum    = (int*)alloc((size_t)256 * 4);
  int* boff    = (int*)alloc((size_t)256 * 4);
  (void)ws_size;

  bf16* xbf = feat0;   // dead before aggregate<0> writes feat0

  const int NB = (N + SCAN_CHUNK - 1) / SCAN_CHUNK;   // 49 (<=64)

  // ---- edge normalize + CSR build ----
  hipMemsetAsync(counts, 0, (size_t)N * 4, stream);
  convert_count<<<(E + 255) / 256, 256, 0, stream>>>(ei, esrc, edst, counts, E);
  scan_pass1<<<NB, SCAN_T, 0, stream>>>(counts, bsum, N);
  scan_pass2<<<1, 64, 0, stream>>>(bsum, boff, NB);
  scan_pass3<<<NB, SCAN_T, 0, stream>>>(counts, boff, row_ptr, cursor, N, Etot);
  scatter_kernel<<<(Etot + 255) / 256, 256, 0, stream>>>(esrc, edst, cursor, col, N, E);

  // ---- prep: bf16 conversions / transposes ----
  convert_pad_x<<<((N * K0P) + 255) / 256, 256, 0, stream>>>(x, xbf, N, 165, K0P);
  transpose_w<<<((HF * K0P) + 255) / 256, 256, 0, stream>>>(W[0], W0t, 165, HF, K0P);
  transpose_w<<<((HF * HF) + 255) / 256, 256, 0, stream>>>(W[1], W1t, HF, HF, HF);
  transpose_w<<<((HF * HF) + 255) / 256, 256, 0, stream>>>(W[2], W2t, HF, HF, HF);

  dim3 ggrid((N + 127) / 128, HF / 128);
  const int aggBlocks  = (N + 3) / 4;
  const int waveBlocks = (N + 3) / 4;

  // ---- layer 0 ----
  gemm_mfma<<<ggrid, 256, 0, stream>>>(xbf, W0t, hbuf, As[0], Ad[0],
                                       alpha_s, alpha_d, N, HF, K0P);
  aggregate_kernel<0><<<aggBlocks, 256, 0, stream>>>(row_ptr, col, hbuf, alpha_s, alpha_d,
                                                     nullptr, Bi[0], Lg[0], Lb[0], feat0, N);

  // ---- layer 1 (in-place residual) ----
  gemm_mfma<<<ggrid, 256, 0, stream>>>(feat0, W1t, hbuf, As[1], Ad[1],
                                       alpha_s, alpha_d, N, HF, HF);
  aggregate_kernel<1><<<aggBlocks, 256, 0, stream>>>(row_ptr, col, hbuf, alpha_s, alpha_d,
                                                     feat0, Bi[1], Lg[1], Lb[1], feat0, N);

  // ---- layer 2 (head mean) ----
  gemm_mfma<<<ggrid, 256, 0, stream>>>(feat0, W2t, hbuf, As[2], Ad[2],
                                       alpha_s, alpha_d, N, HF, HF);
  aggregate_kernel<2><<<aggBlocks, 256, 0, stream>>>(row_ptr, col, hbuf, alpha_s, alpha_d,
                                                     nullptr, Bi[2], Lg[2], Lb[2], bufD, N);

  final_linear_kernel<<<waveBlocks, 256, 0, stream>>>(bufD, lin_w, lin_b, (float*)d_out, N);
}

// Round 7
// 477.032 us; speedup vs baseline: 1.0824x; 1.0824x over previous
//
#include <hip/hip_runtime.h>
#include <hip/hip_bf16.h>
#include <cstdint>
#include <cstddef>

#define HEADS 8
#define HID 64
#define HF 512              // HEADS*HID
#define NEG_SLOPE 0.2f
#define LN_EPS 1e-5f

typedef __hip_bfloat16 bf16;
typedef __attribute__((ext_vector_type(8))) __bf16 bf16v8;
typedef __attribute__((ext_vector_type(4))) float f32x4;

// ---------------- helpers ---------------------------------------------------
__device__ __forceinline__ float wsum64(float v) {
#pragma unroll
  for (int o = 32; o > 0; o >>= 1) v += __shfl_xor(v, o, 64);
  return v;
}
__device__ __forceinline__ int wsum64i(int v) {
#pragma unroll
  for (int o = 32; o > 0; o >>= 1) v += __shfl_xor(v, o, 64);
  return v;
}
__device__ __forceinline__ float leaky(float v) { return v >= 0.f ? v : NEG_SLOPE * v; }
__device__ __forceinline__ float bits2f(unsigned short u) {
  return __uint_as_float(((unsigned)u) << 16);
}
__device__ __forceinline__ unsigned short f2bits(float x) {
  union { bf16 h; unsigned short u; } bu;
  bu.h = __float2bfloat16(x);
  return bu.u;
}
// async global->LDS, 16B per lane (lds dest = wave-uniform base + lane*16)
__device__ __forceinline__ void gload_lds16(const bf16* src, short* lds_base) {
  __builtin_amdgcn_global_load_lds(
      (const __attribute__((address_space(1))) unsigned int*)src,
      (__attribute__((address_space(3))) unsigned int*)lds_base, 16, 0, 0);
}

// ---------------- edge normalize + count (handles int64 or int32) -----------
__global__ __launch_bounds__(256)
void convert_count(const int* __restrict__ ei, int* __restrict__ esrc,
                   int* __restrict__ edst, int* __restrict__ counts, int E) {
  int e = blockIdx.x * 256 + threadIdx.x;
  if (e >= E) return;
  bool i64 = (ei[1] == 0) && (ei[3] == 0) && (ei[5] == 0) && (ei[7] == 0);
  int s, d;
  if (i64) { s = ei[2 * (size_t)e]; d = ei[2 * ((size_t)E + e)]; }
  else     { s = ei[e];             d = ei[E + e]; }
  esrc[e] = s; edst[e] = d;
  atomicAdd(&counts[d], 1);
}

// ---------------- hierarchical exclusive scan over (counts[i]+1) ------------
#define SCAN_T 256
#define SCAN_EPT 4
#define SCAN_CHUNK (SCAN_T * SCAN_EPT)   // 1024

__global__ __launch_bounds__(SCAN_T)
void scan_pass1(const int* __restrict__ counts, int* __restrict__ bsum, int N) {
  int b = blockIdx.x, t = threadIdx.x;
  int base = b * SCAN_CHUNK + t * SCAN_EPT;
  int s = 0;
#pragma unroll
  for (int i = 0; i < SCAN_EPT; ++i) {
    int idx = base + i;
    if (idx < N) s += counts[idx] + 1;
  }
  int lane = t & 63, w = t >> 6;
  int tot = wsum64i(s);
  __shared__ int ws[4];
  if (lane == 0) ws[w] = tot;
  __syncthreads();
  if (t == 0) bsum[b] = ws[0] + ws[1] + ws[2] + ws[3];
}

__global__ __launch_bounds__(64)
void scan_pass2(const int* __restrict__ bsum, int* __restrict__ boff, int NB) {
  int t = threadIdx.x;
  int own = t < NB ? bsum[t] : 0;
  int v = own;
#pragma unroll
  for (int o = 1; o < 64; o <<= 1) {
    int u = __shfl_up(v, o, 64);
    if (t >= o) v += u;
  }
  if (t < NB) boff[t] = v - own;   // exclusive
}

__global__ __launch_bounds__(SCAN_T)
void scan_pass3(const int* __restrict__ counts, const int* __restrict__ boff,
                int* __restrict__ row_ptr, int* __restrict__ cursor, int N, int Etot) {
  int b = blockIdx.x, t = threadIdx.x;
  int base = b * SCAN_CHUNK + t * SCAN_EPT;
  int c[SCAN_EPT];
  int s = 0;
#pragma unroll
  for (int i = 0; i < SCAN_EPT; ++i) {
    int idx = base + i;
    c[i] = idx < N ? counts[idx] + 1 : 0;
    s += c[i];
  }
  int lane = t & 63, w = t >> 6;
  int inc = s;
#pragma unroll
  for (int o = 1; o < 64; o <<= 1) {
    int u = __shfl_up(inc, o, 64);
    if (lane >= o) inc += u;
  }
  __shared__ int wsums[4];
  if (lane == 63) wsums[w] = inc;
  __syncthreads();
  int woff = 0;
  for (int i = 0; i < w; ++i) woff += wsums[i];
  int run = inc - s + woff + boff[b];
#pragma unroll
  for (int i = 0; i < SCAN_EPT; ++i) {
    int idx = base + i;
    if (idx < N) { row_ptr[idx] = run; cursor[idx] = run; run += c[i]; }
  }
  if (b == 0 && t == 0) row_ptr[N] = Etot;
}

__global__ __launch_bounds__(256)
void scatter_kernel(const int* __restrict__ esrc, const int* __restrict__ edst,
                    int* __restrict__ cursor, int* __restrict__ col, int N, int E) {
  int e = blockIdx.x * 256 + threadIdx.x;
  int Etot = E + N;
  if (e >= Etot) return;
  int s = e < E ? esrc[e] : e - E;
  int d = e < E ? edst[e] : e - E;
  int pos = atomicAdd(&cursor[d], 1);
  col[pos] = s;
}

// ---------------- prep: x -> bf16 padded; W -> W^T bf16 padded ---------------
__global__ __launch_bounds__(256)
void convert_pad_x(const float* __restrict__ x, bf16* __restrict__ xbf,
                   int M, int K, int Kp) {
  int idx = blockIdx.x * 256 + threadIdx.x;
  if (idx >= M * Kp) return;
  int row = idx / Kp, colk = idx - row * Kp;
  float v = colk < K ? x[(size_t)row * K + colk] : 0.f;
  xbf[idx] = __float2bfloat16(v);
}

__global__ __launch_bounds__(256)
void transpose_w(const float* __restrict__ W, bf16* __restrict__ Wt,
                 int K, int Ncols, int Kp) {
  int idx = blockIdx.x * 256 + threadIdx.x;
  if (idx >= Ncols * Kp) return;
  int n = idx / Kp, k = idx - n * Kp;
  float v = k < K ? W[(size_t)k * Ncols + n] : 0.f;
  Wt[idx] = __float2bfloat16(v);
}

// ---------------- MFMA GEMM + fused alpha epilogue ---------------------------
// C[M,512] = A[M,K](bf16) @ Bt[512,K](bf16)^T ; alpha_s/d[M,8] = h . a
// Staging via global_load_lds, linear LDS [128][32] shorts, XOR slot swizzle
// (slot = c4 ^ ((r>>1)&3)) applied on BOTH global-source and ds_read sides.
__global__ __launch_bounds__(256)
void gemm_mfma(const bf16* __restrict__ A, const bf16* __restrict__ Bt,
               bf16* __restrict__ C,
               const float* __restrict__ as_g, const float* __restrict__ ad_g,
               float* __restrict__ alpha_s, float* __restrict__ alpha_d,
               int M, int Ncols, int K) {
  __shared__ short Alds[128 * 32];
  __shared__ short Blds[128 * 32];
  const int tid = threadIdx.x;
  const int wave = tid >> 6, lane = tid & 63;
  const int wr = wave >> 1, wc = wave & 1;
  const int row0 = blockIdx.x * 128, col0 = blockIdx.y * 128;
  const int lrow = lane & 15;
  const int kc = lane >> 4;
  // staging geometry: lane -> (r = rbase + lane>>2, c4 = lane&3)
  const int sr = lane >> 2, sc4 = lane & 3;
  f32x4 acc[4][4] = {};

  for (int k0 = 0; k0 < K; k0 += 32) {
#pragma unroll
    for (int i = 0; i < 2; ++i) {
      int rbase = (wave + i * 4) * 16;       // 16 rows per wave-issue
      int r = rbase + sr;
      int slot = sc4 ^ ((r >> 1) & 3);       // inverse-swizzled global source
      int gm = row0 + r; if (gm >= M) gm = M - 1;
      gload_lds16(A + (size_t)gm * K + k0 + slot * 8, &Alds[rbase * 32]);
      gload_lds16(Bt + (size_t)(col0 + r) * K + k0 + slot * 8, &Blds[rbase * 32]);
    }
    __syncthreads();
    bf16v8 af[4], bfr[4];
#pragma unroll
    for (int r = 0; r < 4; ++r) {
      int row = wr * 64 + r * 16 + lrow;
      af[r] = *reinterpret_cast<const bf16v8*>(
          &Alds[row * 32 + ((kc ^ ((row >> 1) & 3)) << 3)]);
    }
#pragma unroll
    for (int c = 0; c < 4; ++c) {
      int row = wc * 64 + c * 16 + lrow;
      bfr[c] = *reinterpret_cast<const bf16v8*>(
          &Blds[row * 32 + ((kc ^ ((row >> 1) & 3)) << 3)]);
    }
#pragma unroll
    for (int r = 0; r < 4; ++r)
#pragma unroll
      for (int c = 0; c < 4; ++c)
        acc[r][c] = __builtin_amdgcn_mfma_f32_16x16x32_bf16(af[r], bfr[c], acc[r][c], 0, 0, 0);
    __syncthreads();
  }

  // C write: C/D layout col=lane&15, row=(lane>>4)*4+j  [m89]
  const int crow = (lane >> 4) * 4;
  const int ccol = lane & 15;
#pragma unroll
  for (int r = 0; r < 4; ++r) {
#pragma unroll
    for (int c = 0; c < 4; ++c) {
      int gc = col0 + wc * 64 + c * 16 + ccol;
#pragma unroll
      for (int j = 0; j < 4; ++j) {
        int gr = row0 + wr * 64 + r * 16 + crow + j;
        if (gr < M) C[(size_t)gr * Ncols + gc] = __float2bfloat16(acc[r][c][j]);
      }
    }
  }

  // fused alpha epilogue: this wave's 64 cols = head (col0+wc*64)>>6
  const int head = (col0 + wc * 64) >> 6;
  float asf[4], adf[4];
#pragma unroll
  for (int c = 0; c < 4; ++c) {
    asf[c] = as_g[head * HID + c * 16 + ccol];
    adf[c] = ad_g[head * HID + c * 16 + ccol];
  }
#pragma unroll
  for (int r = 0; r < 4; ++r) {
#pragma unroll
    for (int j = 0; j < 4; ++j) {
      float ps = 0.f, pd = 0.f;
#pragma unroll
      for (int c = 0; c < 4; ++c) {
        ps = fmaf(acc[r][c][j], asf[c], ps);
        pd = fmaf(acc[r][c][j], adf[c], pd);
      }
#pragma unroll
      for (int o = 1; o < 16; o <<= 1) {
        ps += __shfl_xor(ps, o, 64);
        pd += __shfl_xor(pd, o, 64);
      }
      if (ccol == 0) {
        int gr = row0 + wr * 64 + r * 16 + crow + j;
        if (gr < M) {
          alpha_s[gr * HEADS + head] = ps;
          alpha_d[gr * HEADS + head] = pd;
        }
      }
    }
  }
}

// ---------------- fused aggregate (online softmax, 4-edge groups) -----------
// ONE WAVE per node: lane owns 8 features, head = lane>>3. 4 nodes / block.
// 4 gathers issued per group -> 4x memory-level parallelism, 1 rescale/group.
template <int LAYER>
__global__ __launch_bounds__(256)
void aggregate_kernel(const int* __restrict__ row_ptr, const int* __restrict__ col,
                      const bf16* __restrict__ hbuf,
                      const float* __restrict__ alpha_s, const float* __restrict__ alpha_d,
                      const bf16* __restrict__ resid,
                      const float* __restrict__ bias, const float* __restrict__ g,
                      const float* __restrict__ b,
                      bf16* __restrict__ out_bf, int N) {
  int w = threadIdx.x >> 6;
  int lane = threadIdx.x & 63;
  int nn = blockIdx.x * 4 + w;
  bool valid = nn < N;
  int n = valid ? nn : 0;
  int h = lane >> 3;
  float adh = alpha_d[n * HEADS + h];
  float m = -1e30f, den = 0.f;
  float a[8] = {};
  int lo = row_ptr[n], hi = row_ptr[n + 1];

  for (int j = lo; j < hi; j += 4) {
    int nrem = hi - j;
    // issue all 4 gathers up front (clamped slots re-read edge lo)
    int s0 = col[j];
    int s1 = col[nrem > 1 ? j + 1 : lo];
    int s2 = col[nrem > 2 ? j + 2 : lo];
    int s3 = col[nrem > 3 ? j + 3 : lo];
    float as0 = alpha_s[s0 * HEADS + h];
    float as1 = alpha_s[s1 * HEADS + h];
    float as2 = alpha_s[s2 * HEADS + h];
    float as3 = alpha_s[s3 * HEADS + h];
    uint4 u0 = *reinterpret_cast<const uint4*>(hbuf + (size_t)s0 * HF + lane * 8);
    uint4 u1 = *reinterpret_cast<const uint4*>(hbuf + (size_t)s1 * HF + lane * 8);
    uint4 u2 = *reinterpret_cast<const uint4*>(hbuf + (size_t)s2 * HF + lane * 8);
    uint4 u3 = *reinterpret_cast<const uint4*>(hbuf + (size_t)s3 * HF + lane * 8);
    float e0 = leaky(as0 + adh);
    float e1 = nrem > 1 ? leaky(as1 + adh) : -1e30f;
    float e2 = nrem > 2 ? leaky(as2 + adh) : -1e30f;
    float e3 = nrem > 3 ? leaky(as3 + adh) : -1e30f;
    float gmx = fmaxf(fmaxf(e0, e1), fmaxf(e2, e3));
    if (gmx > m) {                       // single rescale per group
      float sc = __expf(m - gmx);
      den *= sc;
#pragma unroll
      for (int i = 0; i < 8; ++i) a[i] *= sc;
      m = gmx;
    }
    float x0 = __expf(e0 - m);
    float x1 = nrem > 1 ? __expf(e1 - m) : 0.f;
    float x2 = nrem > 2 ? __expf(e2 - m) : 0.f;
    float x3 = nrem > 3 ? __expf(e3 - m) : 0.f;
    den += (x0 + x1) + (x2 + x3);
    const unsigned short* p0 = reinterpret_cast<const unsigned short*>(&u0);
    const unsigned short* p1 = reinterpret_cast<const unsigned short*>(&u1);
    const unsigned short* p2 = reinterpret_cast<const unsigned short*>(&u2);
    const unsigned short* p3 = reinterpret_cast<const unsigned short*>(&u3);
#pragma unroll
    for (int i = 0; i < 8; ++i) {
      float t = fmaf(x0, bits2f(p0[i]), fmaf(x1, bits2f(p1[i]),
                fmaf(x2, bits2f(p2[i]), x3 * bits2f(p3[i]))));
      a[i] += t;
    }
  }
  float inv = 1.f / den;
#pragma unroll
  for (int i = 0; i < 8; ++i) a[i] *= inv;

  if (LAYER < 2) {
    float4 b0 = ((const float4*)bias)[lane * 2];
    float4 b1 = ((const float4*)bias)[lane * 2 + 1];
    a[0] += b0.x; a[1] += b0.y; a[2] += b0.z; a[3] += b0.w;
    a[4] += b1.x; a[5] += b1.y; a[6] += b1.z; a[7] += b1.w;
    if (LAYER == 1) {
      uint4 rr = *reinterpret_cast<const uint4*>(resid + (size_t)n * HF + lane * 8);
      const unsigned short* rs = reinterpret_cast<const unsigned short*>(&rr);
#pragma unroll
      for (int i = 0; i < 8; ++i) a[i] += bits2f(rs[i]);
    }
    float s = 0.f, ss = 0.f;
#pragma unroll
    for (int i = 0; i < 8; ++i) { s += a[i]; ss += a[i] * a[i]; }
    s = wsum64(s); ss = wsum64(ss);
    float mu = s * (1.f / HF);
    float var = ss * (1.f / HF) - mu * mu;
    float rs = rsqrtf(var + LN_EPS);
    float4 g0 = ((const float4*)g)[lane * 2], g1 = ((const float4*)g)[lane * 2 + 1];
    float4 e0 = ((const float4*)b)[lane * 2], e1 = ((const float4*)b)[lane * 2 + 1];
    float gg[8] = {g0.x, g0.y, g0.z, g0.w, g1.x, g1.y, g1.z, g1.w};
    float be[8] = {e0.x, e0.y, e0.z, e0.w, e1.x, e1.y, e1.z, e1.w};
    unsigned short o[8];
#pragma unroll
    for (int i = 0; i < 8; ++i)
      o[i] = f2bits(fmaxf((a[i] - mu) * rs * gg[i] + be[i], 0.f));
    if (valid)
      *reinterpret_cast<uint4*>(out_bf + (size_t)n * HF + lane * 8) =
          *reinterpret_cast<const uint4*>(o);
  } else {
    // head mean via per-wave LDS slab (same-wave write->read, no barrier)
    __shared__ float lds[4][HF];
#pragma unroll
    for (int i = 0; i < 8; ++i) lds[w][lane * 8 + i] = a[i];
    float v = 0.f;
#pragma unroll
    for (int hh = 0; hh < HEADS; ++hh) v += lds[w][hh * HID + lane];
    v = v * (1.f / HEADS) + bias[lane];
    float s = wsum64(v);
    float ss = wsum64(v * v);
    float mu = s * (1.f / HID);
    float var = ss * (1.f / HID) - mu * mu;
    float rs = rsqrtf(var + LN_EPS);
    v = fmaxf((v - mu) * rs * g[lane] + b[lane], 0.f);
    if (valid) out_bf[(size_t)n * HID + lane] = __float2bfloat16(v);
  }
}

// ---------------- final linear: [N,64]bf16 @ [64,2] + b ---------------------
__global__ __launch_bounds__(256)
void final_linear_kernel(const bf16* __restrict__ D, const float* __restrict__ w,
                         const float* __restrict__ bb, float* __restrict__ out, int N) {
  int wid = (blockIdx.x * 256 + threadIdx.x) >> 6;
  int lane = threadIdx.x & 63;
  if (wid >= N) return;
  float v = __bfloat162float(D[(size_t)wid * HID + lane]);
  float s0 = wsum64(v * w[lane * 2 + 0]);
  float s1 = wsum64(v * w[lane * 2 + 1]);
  if (lane == 0) {
    out[(size_t)wid * 2 + 0] = s0 + bb[0];
    out[(size_t)wid * 2 + 1] = s1 + bb[1];
  }
}

// ===========================================================================
extern "C" void kernel_launch(void* const* d_in, const int* in_sizes, int n_in,
                              void* d_out, int out_size, void* d_ws, size_t ws_size,
                              hipStream_t stream) {
  const float* x  = (const float*)d_in[0];
  const int*   ei = (const int*)d_in[1];
  const int N = in_sizes[0] / 165;       // 50000
  const int E = in_sizes[1] / 2;         // 400000
  const int Etot = E + N;
  const int K0P = 192;

  const float* W[3]  = {(const float*)d_in[2],  (const float*)d_in[8],  (const float*)d_in[14]};
  const float* As[3] = {(const float*)d_in[3],  (const float*)d_in[9],  (const float*)d_in[15]};
  const float* Ad[3] = {(const float*)d_in[4],  (const float*)d_in[10], (const float*)d_in[16]};
  const float* Bi[3] = {(const float*)d_in[5],  (const float*)d_in[11], (const float*)d_in[17]};
  const float* Lg[3] = {(const float*)d_in[6],  (const float*)d_in[12], (const float*)d_in[18]};
  const float* Lb[3] = {(const float*)d_in[7],  (const float*)d_in[13], (const float*)d_in[19]};
  const float* lin_w = (const float*)d_in[20];
  const float* lin_b = (const float*)d_in[21];

  // ---- workspace carve-up ----
  char* p = (char*)d_ws;
  auto alloc = [&](size_t bytes) {
    char* r = p;
    p += (bytes + 255) & ~(size_t)255;
    return r;
  };
  bf16* feat0   = (bf16*)alloc((size_t)N * HF * 2);   // layer outputs; aliases xbf
  bf16* hbuf    = (bf16*)alloc((size_t)N * HF * 2);
  bf16* bufD    = (bf16*)alloc((size_t)N * HID * 2);
  float* alpha_s = (float*)alloc((size_t)N * HEADS * 4);
  float* alpha_d = (float*)alloc((size_t)N * HEADS * 4);
  bf16* W0t = (bf16*)alloc((size_t)HF * K0P * 2);
  bf16* W1t = (bf16*)alloc((size_t)HF * HF * 2);
  bf16* W2t = (bf16*)alloc((size_t)HF * HF * 2);
  int* esrc    = (int*)alloc((size_t)E * 4);
  int* edst    = (int*)alloc((size_t)E * 4);
  int* counts  = (int*)alloc((size_t)N * 4);
  int* row_ptr = (int*)alloc((size_t)(N + 1) * 4);
  int* cursor  = (int*)alloc((size_t)N * 4);
  int* col     = (int*)alloc((size_t)Etot * 4);
  int* bsum    = (int*)alloc((size_t)256 * 4);
  int* boff    = (int*)alloc((size_t)256 * 4);
  (void)ws_size;

  bf16* xbf = feat0;   // dead before aggregate<0> writes feat0

  const int NB = (N + SCAN_CHUNK - 1) / SCAN_CHUNK;   // 49 (<=64)

  // ---- edge normalize + CSR build ----
  hipMemsetAsync(counts, 0, (size_t)N * 4, stream);
  convert_count<<<(E + 255) / 256, 256, 0, stream>>>(ei, esrc, edst, counts, E);
  scan_pass1<<<NB, SCAN_T, 0, stream>>>(counts, bsum, N);
  scan_pass2<<<1, 64, 0, stream>>>(bsum, boff, NB);
  scan_pass3<<<NB, SCAN_T, 0, stream>>>(counts, boff, row_ptr, cursor, N, Etot);
  scatter_kernel<<<(Etot + 255) / 256, 256, 0, stream>>>(esrc, edst, cursor, col, N, E);

  // ---- prep: bf16 conversions / transposes ----
  convert_pad_x<<<((N * K0P) + 255) / 256, 256, 0, stream>>>(x, xbf, N, 165, K0P);
  transpose_w<<<((HF * K0P) + 255) / 256, 256, 0, stream>>>(W[0], W0t, 165, HF, K0P);
  transpose_w<<<((HF * HF) + 255) / 256, 256, 0, stream>>>(W[1], W1t, HF, HF, HF);
  transpose_w<<<((HF * HF) + 255) / 256, 256, 0, stream>>>(W[2], W2t, HF, HF, HF);

  dim3 ggrid((N + 127) / 128, HF / 128);
  const int aggBlocks  = (N + 3) / 4;
  const int waveBlocks = (N + 3) / 4;

  // ---- layer 0 ----
  gemm_mfma<<<ggrid, 256, 0, stream>>>(xbf, W0t, hbuf, As[0], Ad[0],
                                       alpha_s, alpha_d, N, HF, K0P);
  aggregate_kernel<0><<<aggBlocks, 256, 0, stream>>>(row_ptr, col, hbuf, alpha_s, alpha_d,
                                                     nullptr, Bi[0], Lg[0], Lb[0], feat0, N);

  // ---- layer 1 (in-place residual) ----
  gemm_mfma<<<ggrid, 256, 0, stream>>>(feat0, W1t, hbuf, As[1], Ad[1],
                                       alpha_s, alpha_d, N, HF, HF);
  aggregate_kernel<1><<<aggBlocks, 256, 0, stream>>>(row_ptr, col, hbuf, alpha_s, alpha_d,
                                                     feat0, Bi[1], Lg[1], Lb[1], feat0, N);

  // ---- layer 2 (head mean) ----
  gemm_mfma<<<ggrid, 256, 0, stream>>>(feat0, W2t, hbuf, As[2], Ad[2],
                                       alpha_s, alpha_d, N, HF, HF);
  aggregate_kernel<2><<<aggBlocks, 256, 0, stream>>>(row_ptr, col, hbuf, alpha_s, alpha_d,
                                                     nullptr, Bi[2], Lg[2], Lb[2], bufD, N);

  final_linear_kernel<<<waveBlocks, 256, 0, stream>>>(bufD, lin_w, lin_b, (float*)d_out, N);
}

// Round 8
// 439.468 us; speedup vs baseline: 1.1750x; 1.0855x over previous
//
#include <hip/hip_runtime.h>
#include <hip/hip_bf16.h>
#include <cstdint>
#include <cstddef>

#define HEADS 8
#define HID 64
#define HF 512              // HEADS*HID
#define NEG_SLOPE 0.2f
#define LN_EPS 1e-5f

typedef __hip_bfloat16 bf16;
typedef __attribute__((ext_vector_type(8))) __bf16 bf16v8;
typedef __attribute__((ext_vector_type(4))) float f32x4;

// ---------------- helpers ---------------------------------------------------
__device__ __forceinline__ float wsum64(float v) {
#pragma unroll
  for (int o = 32; o > 0; o >>= 1) v += __shfl_xor(v, o, 64);
  return v;
}
__device__ __forceinline__ int wsum64i(int v) {
#pragma unroll
  for (int o = 32; o > 0; o >>= 1) v += __shfl_xor(v, o, 64);
  return v;
}
__device__ __forceinline__ float leaky(float v) { return v >= 0.f ? v : NEG_SLOPE * v; }
__device__ __forceinline__ float bits2f(unsigned short u) {
  return __uint_as_float(((unsigned)u) << 16);
}
__device__ __forceinline__ unsigned short f2bits(float x) {
  union { bf16 h; unsigned short u; } bu;
  bu.h = __float2bfloat16(x);
  return bu.u;
}
// async global->LDS, 16B per lane (lds dest = wave-uniform base + lane*16)
__device__ __forceinline__ void gload_lds16(const bf16* src, short* lds_base) {
  __builtin_amdgcn_global_load_lds(
      (const __attribute__((address_space(1))) unsigned int*)src,
      (__attribute__((address_space(3))) unsigned int*)lds_base, 16, 0, 0);
}

// ---------------- edge normalize + count (handles int64 or int32) -----------
__global__ __launch_bounds__(256)
void convert_count(const int* __restrict__ ei, int* __restrict__ esrc,
                   int* __restrict__ edst, int* __restrict__ counts, int E) {
  int e = blockIdx.x * 256 + threadIdx.x;
  if (e >= E) return;
  bool i64 = (ei[1] == 0) && (ei[3] == 0) && (ei[5] == 0) && (ei[7] == 0);
  int s, d;
  if (i64) { s = ei[2 * (size_t)e]; d = ei[2 * ((size_t)E + e)]; }
  else     { s = ei[e];             d = ei[E + e]; }
  esrc[e] = s; edst[e] = d;
  atomicAdd(&counts[d], 1);
}

// ---------------- hierarchical exclusive scan over (counts[i]+1) ------------
#define SCAN_T 256
#define SCAN_EPT 4
#define SCAN_CHUNK (SCAN_T * SCAN_EPT)   // 1024

__global__ __launch_bounds__(SCAN_T)
void scan_pass1(const int* __restrict__ counts, int* __restrict__ bsum, int N) {
  int b = blockIdx.x, t = threadIdx.x;
  int base = b * SCAN_CHUNK + t * SCAN_EPT;
  int s = 0;
#pragma unroll
  for (int i = 0; i < SCAN_EPT; ++i) {
    int idx = base + i;
    if (idx < N) s += counts[idx] + 1;
  }
  int lane = t & 63, w = t >> 6;
  int tot = wsum64i(s);
  __shared__ int ws[4];
  if (lane == 0) ws[w] = tot;
  __syncthreads();
  if (t == 0) bsum[b] = ws[0] + ws[1] + ws[2] + ws[3];
}

__global__ __launch_bounds__(64)
void scan_pass2(const int* __restrict__ bsum, int* __restrict__ boff, int NB) {
  int t = threadIdx.x;
  int own = t < NB ? bsum[t] : 0;
  int v = own;
#pragma unroll
  for (int o = 1; o < 64; o <<= 1) {
    int u = __shfl_up(v, o, 64);
    if (t >= o) v += u;
  }
  if (t < NB) boff[t] = v - own;   // exclusive
}

__global__ __launch_bounds__(SCAN_T)
void scan_pass3(const int* __restrict__ counts, const int* __restrict__ boff,
                int* __restrict__ row_ptr, int* __restrict__ cursor, int N, int Etot) {
  int b = blockIdx.x, t = threadIdx.x;
  int base = b * SCAN_CHUNK + t * SCAN_EPT;
  int c[SCAN_EPT];
  int s = 0;
#pragma unroll
  for (int i = 0; i < SCAN_EPT; ++i) {
    int idx = base + i;
    c[i] = idx < N ? counts[idx] + 1 : 0;
    s += c[i];
  }
  int lane = t & 63, w = t >> 6;
  int inc = s;
#pragma unroll
  for (int o = 1; o < 64; o <<= 1) {
    int u = __shfl_up(inc, o, 64);
    if (lane >= o) inc += u;
  }
  __shared__ int wsums[4];
  if (lane == 63) wsums[w] = inc;
  __syncthreads();
  int woff = 0;
  for (int i = 0; i < w; ++i) woff += wsums[i];
  int run = inc - s + woff + boff[b];
#pragma unroll
  for (int i = 0; i < SCAN_EPT; ++i) {
    int idx = base + i;
    if (idx < N) { row_ptr[idx] = run; cursor[idx] = run; run += c[i]; }
  }
  if (b == 0 && t == 0) row_ptr[N] = Etot;
}

__global__ __launch_bounds__(256)
void scatter_kernel(const int* __restrict__ esrc, const int* __restrict__ edst,
                    int* __restrict__ cursor, int* __restrict__ col, int N, int E) {
  int e = blockIdx.x * 256 + threadIdx.x;
  int Etot = E + N;
  if (e >= Etot) return;
  int s = e < E ? esrc[e] : e - E;
  int d = e < E ? edst[e] : e - E;
  int pos = atomicAdd(&cursor[d], 1);
  col[pos] = s;
}

// ---------------- merged prep: x->bf16 pad + 3x W->W^T bf16 -----------------
__global__ __launch_bounds__(256)
void prep_kernel(const float* __restrict__ x, bf16* __restrict__ xbf,
                 const float* __restrict__ W0, bf16* __restrict__ W0t,
                 const float* __restrict__ W1, bf16* __restrict__ W1t,
                 const float* __restrict__ W2, bf16* __restrict__ W2t,
                 int N, int K0P) {
  const int S0 = N * K0P;            // xbf
  const int S1 = HF * K0P;           // W0t
  const int S2 = HF * HF;            // W1t / W2t
  int idx = blockIdx.x * 256 + threadIdx.x;
  if (idx < S0) {
    int row = idx / K0P, colk = idx - row * K0P;
    float v = colk < 165 ? x[(size_t)row * 165 + colk] : 0.f;
    xbf[idx] = __float2bfloat16(v);
    return;
  }
  idx -= S0;
  if (idx < S1) {
    int n = idx / K0P, k = idx - n * K0P;
    float v = k < 165 ? W0[(size_t)k * HF + n] : 0.f;
    W0t[idx] = __float2bfloat16(v);
    return;
  }
  idx -= S1;
  if (idx < S2) {
    int n = idx >> 9, k = idx & 511;
    W1t[idx] = __float2bfloat16(W1[(size_t)k * HF + n]);
    return;
  }
  idx -= S2;
  if (idx < S2) {
    int n = idx >> 9, k = idx & 511;
    W2t[idx] = __float2bfloat16(W2[(size_t)k * HF + n]);
  }
}

// ---------------- MFMA GEMM + fused alpha epilogue ---------------------------
// C[M,512] = A[M,K](bf16) @ Bt[512,K](bf16)^T ; alpha_s/d[M,8] = h . a
// 1D grid with XCD-grouping: the 4 col-tiles of one row-tile map to the SAME
// XCD (assuming wgid%8 round-robin) and run concurrently -> A-tile L2 reuse.
__global__ __launch_bounds__(256)
void gemm_mfma(const bf16* __restrict__ A, const bf16* __restrict__ Bt,
               bf16* __restrict__ C,
               const float* __restrict__ as_g, const float* __restrict__ ad_g,
               float* __restrict__ alpha_s, float* __restrict__ alpha_d,
               int M, int Ncols, int K, int RT) {
  // id -> (row tile rt, col tile cco): xcd = id&7 ; q = id>>3 ; c = q&3 ; rq = q>>2
  const int id = blockIdx.x;
  const int xcd = id & 7;
  const int q = id >> 3;
  const int cco = q & 3;
  const int rt = (q >> 2) * 8 + xcd;
  if (rt >= RT) return;                   // uniform across block
  const int row0 = rt * 128, col0 = cco * 128;

  __shared__ short Alds[128 * 32];
  __shared__ short Blds[128 * 32];
  const int tid = threadIdx.x;
  const int wave = tid >> 6, lane = tid & 63;
  const int wr = wave >> 1, wc = wave & 1;
  const int lrow = lane & 15;
  const int kc = lane >> 4;
  const int sr = lane >> 2, sc4 = lane & 3;   // staging: 4 lanes/row
  f32x4 acc[4][4] = {};

  for (int k0 = 0; k0 < K; k0 += 32) {
#pragma unroll
    for (int i = 0; i < 2; ++i) {
      int rbase = (wave + i * 4) * 16;       // 16 rows per wave-issue
      int r = rbase + sr;
      int slot = sc4 ^ ((r >> 1) & 3);       // inverse-swizzled global source
      int gm = row0 + r; if (gm >= M) gm = M - 1;
      gload_lds16(A + (size_t)gm * K + k0 + slot * 8, &Alds[rbase * 32]);
      gload_lds16(Bt + (size_t)(col0 + r) * K + k0 + slot * 8, &Blds[rbase * 32]);
    }
    __syncthreads();
    bf16v8 af[4], bfr[4];
#pragma unroll
    for (int r = 0; r < 4; ++r) {
      int row = wr * 64 + r * 16 + lrow;
      af[r] = *reinterpret_cast<const bf16v8*>(
          &Alds[row * 32 + ((kc ^ ((row >> 1) & 3)) << 3)]);
    }
#pragma unroll
    for (int c = 0; c < 4; ++c) {
      int row = wc * 64 + c * 16 + lrow;
      bfr[c] = *reinterpret_cast<const bf16v8*>(
          &Blds[row * 32 + ((kc ^ ((row >> 1) & 3)) << 3)]);
    }
#pragma unroll
    for (int r = 0; r < 4; ++r)
#pragma unroll
      for (int c = 0; c < 4; ++c)
        acc[r][c] = __builtin_amdgcn_mfma_f32_16x16x32_bf16(af[r], bfr[c], acc[r][c], 0, 0, 0);
    __syncthreads();
  }

  // C write: C/D layout col=lane&15, row=(lane>>4)*4+j  [m89]
  const int crow = (lane >> 4) * 4;
  const int ccol = lane & 15;
#pragma unroll
  for (int r = 0; r < 4; ++r) {
#pragma unroll
    for (int c = 0; c < 4; ++c) {
      int gc = col0 + wc * 64 + c * 16 + ccol;
#pragma unroll
      for (int j = 0; j < 4; ++j) {
        int gr = row0 + wr * 64 + r * 16 + crow + j;
        if (gr < M) C[(size_t)gr * Ncols + gc] = __float2bfloat16(acc[r][c][j]);
      }
    }
  }

  // fused alpha epilogue: this wave's 64 cols = head (col0+wc*64)>>6
  const int head = (col0 + wc * 64) >> 6;
  float asf[4], adf[4];
#pragma unroll
  for (int c = 0; c < 4; ++c) {
    asf[c] = as_g[head * HID + c * 16 + ccol];
    adf[c] = ad_g[head * HID + c * 16 + ccol];
  }
#pragma unroll
  for (int r = 0; r < 4; ++r) {
#pragma unroll
    for (int j = 0; j < 4; ++j) {
      float ps = 0.f, pd = 0.f;
#pragma unroll
      for (int c = 0; c < 4; ++c) {
        ps = fmaf(acc[r][c][j], asf[c], ps);
        pd = fmaf(acc[r][c][j], adf[c], pd);
      }
#pragma unroll
      for (int o = 1; o < 16; o <<= 1) {
        ps += __shfl_xor(ps, o, 64);
        pd += __shfl_xor(pd, o, 64);
      }
      if (ccol == 0) {
        int gr = row0 + wr * 64 + r * 16 + crow + j;
        if (gr < M) {
          alpha_s[gr * HEADS + head] = ps;
          alpha_d[gr * HEADS + head] = pd;
        }
      }
    }
  }
}

// ---------------- fused aggregate (online softmax, 8-edge groups) -----------
// ONE WAVE per node: lane owns 8 features, head = lane>>3. 4 nodes / block.
// 8 gathers issued per group -> 8x memory-level parallelism, 1 rescale/group.
// LAYER 2 additionally fuses head-mean + LN + ReLU + final 64->2 linear.
template <int LAYER>
__global__ __launch_bounds__(256)
void aggregate_kernel(const int* __restrict__ row_ptr, const int* __restrict__ col,
                      const bf16* __restrict__ hbuf,
                      const float* __restrict__ alpha_s, const float* __restrict__ alpha_d,
                      const bf16* __restrict__ resid,
                      const float* __restrict__ bias, const float* __restrict__ g,
                      const float* __restrict__ b,
                      const float* __restrict__ lw, const float* __restrict__ lb,
                      bf16* __restrict__ out_bf, float* __restrict__ out_f, int N) {
  int w = threadIdx.x >> 6;
  int lane = threadIdx.x & 63;
  int nn = blockIdx.x * 4 + w;
  bool valid = nn < N;
  int n = valid ? nn : 0;
  int h = lane >> 3;
  float adh = alpha_d[n * HEADS + h];
  float m = -1e30f, den = 0.f;
  float a[8] = {};
  int lo = row_ptr[n], hi = row_ptr[n + 1];

  for (int j = lo; j < hi; j += 8) {
    int idx[8]; float as[8]; uint4 u[8]; float e[8];
#pragma unroll
    for (int k = 0; k < 8; ++k) idx[k] = col[(j + k < hi) ? j + k : lo];
#pragma unroll
    for (int k = 0; k < 8; ++k) as[k] = alpha_s[idx[k] * HEADS + h];
#pragma unroll
    for (int k = 0; k < 8; ++k)
      u[k] = *reinterpret_cast<const uint4*>(hbuf + (size_t)idx[k] * HF + lane * 8);
#pragma unroll
    for (int k = 0; k < 8; ++k)
      e[k] = (j + k < hi) ? leaky(as[k] + adh) : -1e30f;
    float m01 = fmaxf(e[0], e[1]), m23 = fmaxf(e[2], e[3]);
    float m45 = fmaxf(e[4], e[5]), m67 = fmaxf(e[6], e[7]);
    float gmx = fmaxf(fmaxf(m01, m23), fmaxf(m45, m67));
    if (gmx > m) {                       // single rescale per group
      float sc = __expf(m - gmx);
      den *= sc;
#pragma unroll
      for (int i = 0; i < 8; ++i) a[i] *= sc;
      m = gmx;
    }
    float xk[8];
#pragma unroll
    for (int k = 0; k < 8; ++k) xk[k] = __expf(e[k] - m);   // invalid -> exp(-huge)=0
#pragma unroll
    for (int k = 0; k < 8; ++k) den += xk[k];
#pragma unroll
    for (int k = 0; k < 8; ++k) {
      const unsigned short* pk = reinterpret_cast<const unsigned short*>(&u[k]);
#pragma unroll
      for (int i = 0; i < 8; ++i) a[i] = fmaf(xk[k], bits2f(pk[i]), a[i]);
    }
  }
  float inv = 1.f / den;
#pragma unroll
  for (int i = 0; i < 8; ++i) a[i] *= inv;

  if (LAYER < 2) {
    float4 b0 = ((const float4*)bias)[lane * 2];
    float4 b1 = ((const float4*)bias)[lane * 2 + 1];
    a[0] += b0.x; a[1] += b0.y; a[2] += b0.z; a[3] += b0.w;
    a[4] += b1.x; a[5] += b1.y; a[6] += b1.z; a[7] += b1.w;
    if (LAYER == 1) {
      uint4 rr = *reinterpret_cast<const uint4*>(resid + (size_t)n * HF + lane * 8);
      const unsigned short* rs = reinterpret_cast<const unsigned short*>(&rr);
#pragma unroll
      for (int i = 0; i < 8; ++i) a[i] += bits2f(rs[i]);
    }
    float s = 0.f, ss = 0.f;
#pragma unroll
    for (int i = 0; i < 8; ++i) { s += a[i]; ss += a[i] * a[i]; }
    s = wsum64(s); ss = wsum64(ss);
    float mu = s * (1.f / HF);
    float var = ss * (1.f / HF) - mu * mu;
    float rs = rsqrtf(var + LN_EPS);
    float4 g0 = ((const float4*)g)[lane * 2], g1 = ((const float4*)g)[lane * 2 + 1];
    float4 e0 = ((const float4*)b)[lane * 2], e1 = ((const float4*)b)[lane * 2 + 1];
    float gg[8] = {g0.x, g0.y, g0.z, g0.w, g1.x, g1.y, g1.z, g1.w};
    float be[8] = {e0.x, e0.y, e0.z, e0.w, e1.x, e1.y, e1.z, e1.w};
    unsigned short o[8];
#pragma unroll
    for (int i = 0; i < 8; ++i)
      o[i] = f2bits(fmaxf((a[i] - mu) * rs * gg[i] + be[i], 0.f));
    if (valid)
      *reinterpret_cast<uint4*>(out_bf + (size_t)n * HF + lane * 8) =
          *reinterpret_cast<const uint4*>(o);
  } else {
    // head mean via per-wave LDS slab (same-wave write->read, no barrier)
    __shared__ float lds[4][HF];
#pragma unroll
    for (int i = 0; i < 8; ++i) lds[w][lane * 8 + i] = a[i];
    float v = 0.f;
#pragma unroll
    for (int hh = 0; hh < HEADS; ++hh) v += lds[w][hh * HID + lane];
    v = v * (1.f / HEADS) + bias[lane];
    float s = wsum64(v);
    float ss = wsum64(v * v);
    float mu = s * (1.f / HID);
    float var = ss * (1.f / HID) - mu * mu;
    float rs = rsqrtf(var + LN_EPS);
    v = fmaxf((v - mu) * rs * g[lane] + b[lane], 0.f);
    // fused final linear: [64] @ [64,2] + lb
    float s0 = wsum64(v * lw[lane * 2 + 0]);
    float s1 = wsum64(v * lw[lane * 2 + 1]);
    if (valid && lane == 0) {
      out_f[(size_t)n * 2 + 0] = s0 + lb[0];
      out_f[(size_t)n * 2 + 1] = s1 + lb[1];
    }
  }
}

// ===========================================================================
extern "C" void kernel_launch(void* const* d_in, const int* in_sizes, int n_in,
                              void* d_out, int out_size, void* d_ws, size_t ws_size,
                              hipStream_t stream) {
  const float* x  = (const float*)d_in[0];
  const int*   ei = (const int*)d_in[1];
  const int N = in_sizes[0] / 165;       // 50000
  const int E = in_sizes[1] / 2;         // 400000
  const int Etot = E + N;
  const int K0P = 192;

  const float* W[3]  = {(const float*)d_in[2],  (const float*)d_in[8],  (const float*)d_in[14]};
  const float* As[3] = {(const float*)d_in[3],  (const float*)d_in[9],  (const float*)d_in[15]};
  const float* Ad[3] = {(const float*)d_in[4],  (const float*)d_in[10], (const float*)d_in[16]};
  const float* Bi[3] = {(const float*)d_in[5],  (const float*)d_in[11], (const float*)d_in[17]};
  const float* Lg[3] = {(const float*)d_in[6],  (const float*)d_in[12], (const float*)d_in[18]};
  const float* Lb[3] = {(const float*)d_in[7],  (const float*)d_in[13], (const float*)d_in[19]};
  const float* lin_w = (const float*)d_in[20];
  const float* lin_b = (const float*)d_in[21];

  // ---- workspace carve-up ----
  char* p = (char*)d_ws;
  auto alloc = [&](size_t bytes) {
    char* r = p;
    p += (bytes + 255) & ~(size_t)255;
    return r;
  };
  bf16* feat0   = (bf16*)alloc((size_t)N * HF * 2);   // layer outputs; aliases xbf
  bf16* hbuf    = (bf16*)alloc((size_t)N * HF * 2);
  float* alpha_s = (float*)alloc((size_t)N * HEADS * 4);
  float* alpha_d = (float*)alloc((size_t)N * HEADS * 4);
  bf16* W0t = (bf16*)alloc((size_t)HF * K0P * 2);
  bf16* W1t = (bf16*)alloc((size_t)HF * HF * 2);
  bf16* W2t = (bf16*)alloc((size_t)HF * HF * 2);
  int* esrc    = (int*)alloc((size_t)E * 4);
  int* edst    = (int*)alloc((size_t)E * 4);
  int* counts  = (int*)alloc((size_t)N * 4);
  int* row_ptr = (int*)alloc((size_t)(N + 1) * 4);
  int* cursor  = (int*)alloc((size_t)N * 4);
  int* col     = (int*)alloc((size_t)Etot * 4);
  int* bsum    = (int*)alloc((size_t)256 * 4);
  int* boff    = (int*)alloc((size_t)256 * 4);
  (void)ws_size;

  bf16* xbf = feat0;   // dead before aggregate<0> writes feat0

  const int NB = (N + SCAN_CHUNK - 1) / SCAN_CHUNK;   // 49 (<=64)

  // ---- edge normalize + CSR build ----
  hipMemsetAsync(counts, 0, (size_t)N * 4, stream);
  convert_count<<<(E + 255) / 256, 256, 0, stream>>>(ei, esrc, edst, counts, E);
  scan_pass1<<<NB, SCAN_T, 0, stream>>>(counts, bsum, N);
  scan_pass2<<<1, 64, 0, stream>>>(bsum, boff, NB);
  scan_pass3<<<NB, SCAN_T, 0, stream>>>(counts, boff, row_ptr, cursor, N, Etot);
  scatter_kernel<<<(Etot + 255) / 256, 256, 0, stream>>>(esrc, edst, cursor, col, N, E);

  // ---- merged prep ----
  {
    int total = N * K0P + HF * K0P + 2 * HF * HF;
    prep_kernel<<<(total + 255) / 256, 256, 0, stream>>>(
        x, xbf, W[0], W0t, W[1], W1t, W[2], W2t, N, K0P);
  }

  const int RT  = (N + 127) / 128;                 // 391 row tiles
  const int RTp = ((RT + 7) / 8) * 8;              // 392
  const int gemmBlocks = RTp * 4;                  // XCD-grouped 1D grid
  const int aggBlocks  = (N + 3) / 4;

  // ---- layer 0 ----
  gemm_mfma<<<gemmBlocks, 256, 0, stream>>>(xbf, W0t, hbuf, As[0], Ad[0],
                                            alpha_s, alpha_d, N, HF, K0P, RT);
  aggregate_kernel<0><<<aggBlocks, 256, 0, stream>>>(row_ptr, col, hbuf, alpha_s, alpha_d,
                                                     nullptr, Bi[0], Lg[0], Lb[0],
                                                     nullptr, nullptr, feat0, nullptr, N);

  // ---- layer 1 (in-place residual) ----
  gemm_mfma<<<gemmBlocks, 256, 0, stream>>>(feat0, W1t, hbuf, As[1], Ad[1],
                                            alpha_s, alpha_d, N, HF, HF, RT);
  aggregate_kernel<1><<<aggBlocks, 256, 0, stream>>>(row_ptr, col, hbuf, alpha_s, alpha_d,
                                                     feat0, Bi[1], Lg[1], Lb[1],
                                                     nullptr, nullptr, feat0, nullptr, N);

  // ---- layer 2 (head mean + LN + ReLU + final linear fused) ----
  gemm_mfma<<<gemmBlocks, 256, 0, stream>>>(feat0, W2t, hbuf, As[2], Ad[2],
                                            alpha_s, alpha_d, N, HF, HF, RT);
  aggregate_kernel<2><<<aggBlocks, 256, 0, stream>>>(row_ptr, col, hbuf, alpha_s, alpha_d,
                                                     nullptr, Bi[2], Lg[2], Lb[2],
                                                     lin_w, lin_b, nullptr, (float*)d_out, N);
}

// Round 9
// 435.317 us; speedup vs baseline: 1.1862x; 1.0095x over previous
//
#include <hip/hip_runtime.h>
#include <hip/hip_bf16.h>
#include <cstdint>
#include <cstddef>

#define HEADS 8
#define HID 64
#define HF 512              // HEADS*HID
#define NEG_SLOPE 0.2f
#define LN_EPS 1e-5f

typedef __hip_bfloat16 bf16;
typedef __attribute__((ext_vector_type(8))) __bf16 bf16v8;
typedef __attribute__((ext_vector_type(4))) float f32x4;

// ---------------- helpers ---------------------------------------------------
__device__ __forceinline__ float wsum64(float v) {
#pragma unroll
  for (int o = 32; o > 0; o >>= 1) v += __shfl_xor(v, o, 64);
  return v;
}
__device__ __forceinline__ int wsum64i(int v) {
#pragma unroll
  for (int o = 32; o > 0; o >>= 1) v += __shfl_xor(v, o, 64);
  return v;
}
__device__ __forceinline__ float leaky(float v) { return v >= 0.f ? v : NEG_SLOPE * v; }
__device__ __forceinline__ float bits2f(unsigned short u) {
  return __uint_as_float(((unsigned)u) << 16);
}
__device__ __forceinline__ unsigned short f2bits(float x) {
  union { bf16 h; unsigned short u; } bu;
  bu.h = __float2bfloat16(x);
  return bu.u;
}
// async global->LDS, 16B per lane (lds dest = wave-uniform base + lane*16)
__device__ __forceinline__ void gload_lds16(const bf16* src, short* lds_base) {
  __builtin_amdgcn_global_load_lds(
      (const __attribute__((address_space(1))) unsigned int*)src,
      (__attribute__((address_space(3))) unsigned int*)lds_base, 16, 0, 0);
}

// ---------------- edge normalize + count (handles int64 or int32) -----------
__global__ __launch_bounds__(256)
void convert_count(const int* __restrict__ ei, int* __restrict__ esrc,
                   int* __restrict__ edst, int* __restrict__ counts, int E) {
  int e = blockIdx.x * 256 + threadIdx.x;
  if (e >= E) return;
  bool i64 = (ei[1] == 0) && (ei[3] == 0) && (ei[5] == 0) && (ei[7] == 0);
  int s, d;
  if (i64) { s = ei[2 * (size_t)e]; d = ei[2 * ((size_t)E + e)]; }
  else     { s = ei[e];             d = ei[E + e]; }
  esrc[e] = s; edst[e] = d;
  atomicAdd(&counts[d], 1);
}

// ---------------- hierarchical exclusive scan over (counts[i]+1) ------------
#define SCAN_T 256
#define SCAN_EPT 4
#define SCAN_CHUNK (SCAN_T * SCAN_EPT)   // 1024

__global__ __launch_bounds__(SCAN_T)
void scan_pass1(const int* __restrict__ counts, int* __restrict__ bsum, int N) {
  int b = blockIdx.x, t = threadIdx.x;
  int base = b * SCAN_CHUNK + t * SCAN_EPT;
  int s = 0;
#pragma unroll
  for (int i = 0; i < SCAN_EPT; ++i) {
    int idx = base + i;
    if (idx < N) s += counts[idx] + 1;
  }
  int lane = t & 63, w = t >> 6;
  int tot = wsum64i(s);
  __shared__ int ws[4];
  if (lane == 0) ws[w] = tot;
  __syncthreads();
  if (t == 0) bsum[b] = ws[0] + ws[1] + ws[2] + ws[3];
}

__global__ __launch_bounds__(64)
void scan_pass2(const int* __restrict__ bsum, int* __restrict__ boff, int NB) {
  int t = threadIdx.x;
  int own = t < NB ? bsum[t] : 0;
  int v = own;
#pragma unroll
  for (int o = 1; o < 64; o <<= 1) {
    int u = __shfl_up(v, o, 64);
    if (t >= o) v += u;
  }
  if (t < NB) boff[t] = v - own;   // exclusive
}

__global__ __launch_bounds__(SCAN_T)
void scan_pass3(const int* __restrict__ counts, const int* __restrict__ boff,
                int* __restrict__ row_ptr, int* __restrict__ cursor, int N, int Etot) {
  int b = blockIdx.x, t = threadIdx.x;
  int base = b * SCAN_CHUNK + t * SCAN_EPT;
  int c[SCAN_EPT];
  int s = 0;
#pragma unroll
  for (int i = 0; i < SCAN_EPT; ++i) {
    int idx = base + i;
    c[i] = idx < N ? counts[idx] + 1 : 0;
    s += c[i];
  }
  int lane = t & 63, w = t >> 6;
  int inc = s;
#pragma unroll
  for (int o = 1; o < 64; o <<= 1) {
    int u = __shfl_up(inc, o, 64);
    if (lane >= o) inc += u;
  }
  __shared__ int wsums[4];
  if (lane == 63) wsums[w] = inc;
  __syncthreads();
  int woff = 0;
  for (int i = 0; i < w; ++i) woff += wsums[i];
  int run = inc - s + woff + boff[b];
#pragma unroll
  for (int i = 0; i < SCAN_EPT; ++i) {
    int idx = base + i;
    if (idx < N) { row_ptr[idx] = run; cursor[idx] = run; run += c[i]; }
  }
  if (b == 0 && t == 0) row_ptr[N] = Etot;
}

__global__ __launch_bounds__(256)
void scatter_kernel(const int* __restrict__ esrc, const int* __restrict__ edst,
                    int* __restrict__ cursor, int* __restrict__ col, int N, int E) {
  int e = blockIdx.x * 256 + threadIdx.x;
  int Etot = E + N;
  if (e >= Etot) return;
  int s = e < E ? esrc[e] : e - E;
  int d = e < E ? edst[e] : e - E;
  int pos = atomicAdd(&cursor[d], 1);
  col[pos] = s;
}

// ---------------- merged prep: x->bf16 pad + 3x W->W^T bf16 -----------------
__global__ __launch_bounds__(256)
void prep_kernel(const float* __restrict__ x, bf16* __restrict__ xbf,
                 const float* __restrict__ W0, bf16* __restrict__ W0t,
                 const float* __restrict__ W1, bf16* __restrict__ W1t,
                 const float* __restrict__ W2, bf16* __restrict__ W2t,
                 int N, int K0P) {
  const int S0 = N * K0P;            // xbf
  const int S1 = HF * K0P;           // W0t
  const int S2 = HF * HF;            // W1t / W2t
  int idx = blockIdx.x * 256 + threadIdx.x;
  if (idx < S0) {
    int row = idx / K0P, colk = idx - row * K0P;
    float v = colk < 165 ? x[(size_t)row * 165 + colk] : 0.f;
    xbf[idx] = __float2bfloat16(v);
    return;
  }
  idx -= S0;
  if (idx < S1) {
    int n = idx / K0P, k = idx - n * K0P;
    float v = k < 165 ? W0[(size_t)k * HF + n] : 0.f;
    W0t[idx] = __float2bfloat16(v);
    return;
  }
  idx -= S1;
  if (idx < S2) {
    int n = idx >> 9, k = idx & 511;
    W1t[idx] = __float2bfloat16(W1[(size_t)k * HF + n]);
    return;
  }
  idx -= S2;
  if (idx < S2) {
    int n = idx >> 9, k = idx & 511;
    W2t[idx] = __float2bfloat16(W2[(size_t)k * HF + n]);
  }
}

// ---------------- MFMA GEMM + fused alpha epilogue ---------------------------
// C[M,512] = A[M,K](bf16) @ Bt[512,K](bf16)^T ; alpha_s/d[M,8] = h . a
// XCD-grouped 1D grid (A-panel L2 reuse) + DOUBLE-BUFFERED pipelined staging:
// issue STAGE(buf^1) BEFORE computing buf, single barrier/iter (T3 minimal).
__global__ __launch_bounds__(256)
void gemm_mfma(const bf16* __restrict__ A, const bf16* __restrict__ Bt,
               bf16* __restrict__ C,
               const float* __restrict__ as_g, const float* __restrict__ ad_g,
               float* __restrict__ alpha_s, float* __restrict__ alpha_d,
               int M, int Ncols, int K, int RT) {
  // id -> (row tile rt, col tile cco): xcd = id&7 ; q = id>>3 ; c = q&3 ; rq = q>>2
  const int id = blockIdx.x;
  const int xcd = id & 7;
  const int q = id >> 3;
  const int cco = q & 3;
  const int rt = (q >> 2) * 8 + xcd;
  if (rt >= RT) return;                   // uniform across block
  const int row0 = rt * 128, col0 = cco * 128;

  __shared__ short Alds[2][128 * 32];
  __shared__ short Blds[2][128 * 32];
  const int tid = threadIdx.x;
  const int wave = tid >> 6, lane = tid & 63;
  const int wr = wave >> 1, wc = wave & 1;
  const int lrow = lane & 15;
  const int kc = lane >> 4;
  const int sr = lane >> 2, sc4 = lane & 3;   // staging: 4 lanes/row
  f32x4 acc[4][4] = {};

  // staging: one 128x32 bf16 tile of A and Bt into buffer pb at k-offset k0
  auto stage = [&](int k0, int pb) {
#pragma unroll
    for (int i = 0; i < 2; ++i) {
      int rbase = (wave + i * 4) * 16;       // 16 rows per wave-issue
      int r = rbase + sr;
      int slot = sc4 ^ ((r >> 1) & 3);       // inverse-swizzled global source
      int gm = row0 + r; if (gm >= M) gm = M - 1;
      gload_lds16(A + (size_t)gm * K + k0 + slot * 8, &Alds[pb][rbase * 32]);
      gload_lds16(Bt + (size_t)(col0 + r) * K + k0 + slot * 8, &Blds[pb][rbase * 32]);
    }
  };

  stage(0, 0);
  __syncthreads();                           // drain prologue loads
  int p = 0;
  for (int k0 = 0; k0 < K; k0 += 32) {
    if (k0 + 32 < K) stage(k0 + 32, p ^ 1);  // issue next tile BEFORE compute
    bf16v8 af[4], bfr[4];
#pragma unroll
    for (int r = 0; r < 4; ++r) {
      int row = wr * 64 + r * 16 + lrow;
      af[r] = *reinterpret_cast<const bf16v8*>(
          &Alds[p][row * 32 + ((kc ^ ((row >> 1) & 3)) << 3)]);
    }
#pragma unroll
    for (int c = 0; c < 4; ++c) {
      int row = wc * 64 + c * 16 + lrow;
      bfr[c] = *reinterpret_cast<const bf16v8*>(
          &Blds[p][row * 32 + ((kc ^ ((row >> 1) & 3)) << 3)]);
    }
#pragma unroll
    for (int r = 0; r < 4; ++r)
#pragma unroll
      for (int c = 0; c < 4; ++c)
        acc[r][c] = __builtin_amdgcn_mfma_f32_16x16x32_bf16(af[r], bfr[c], acc[r][c], 0, 0, 0);
    __syncthreads();   // implicit vmcnt(0): staged loads landed; lgkm: reads done
    p ^= 1;
  }

  // C write: C/D layout col=lane&15, row=(lane>>4)*4+j  [m89]
  const int crow = (lane >> 4) * 4;
  const int ccol = lane & 15;
#pragma unroll
  for (int r = 0; r < 4; ++r) {
#pragma unroll
    for (int c = 0; c < 4; ++c) {
      int gc = col0 + wc * 64 + c * 16 + ccol;
#pragma unroll
      for (int j = 0; j < 4; ++j) {
        int gr = row0 + wr * 64 + r * 16 + crow + j;
        if (gr < M) C[(size_t)gr * Ncols + gc] = __float2bfloat16(acc[r][c][j]);
      }
    }
  }

  // fused alpha epilogue: this wave's 64 cols = head (col0+wc*64)>>6
  const int head = (col0 + wc * 64) >> 6;
  float asf[4], adf[4];
#pragma unroll
  for (int c = 0; c < 4; ++c) {
    asf[c] = as_g[head * HID + c * 16 + ccol];
    adf[c] = ad_g[head * HID + c * 16 + ccol];
  }
#pragma unroll
  for (int r = 0; r < 4; ++r) {
#pragma unroll
    for (int j = 0; j < 4; ++j) {
      float ps = 0.f, pd = 0.f;
#pragma unroll
      for (int c = 0; c < 4; ++c) {
        ps = fmaf(acc[r][c][j], asf[c], ps);
        pd = fmaf(acc[r][c][j], adf[c], pd);
      }
#pragma unroll
      for (int o = 1; o < 16; o <<= 1) {
        ps += __shfl_xor(ps, o, 64);
        pd += __shfl_xor(pd, o, 64);
      }
      if (ccol == 0) {
        int gr = row0 + wr * 64 + r * 16 + crow + j;
        if (gr < M) {
          alpha_s[gr * HEADS + head] = ps;
          alpha_d[gr * HEADS + head] = pd;
        }
      }
    }
  }
}

// ---------------- fused aggregate (online softmax, 8-edge groups) -----------
// ONE WAVE per node: lane owns 8 features, head = lane>>3. 4 nodes / block.
// LAYER 2 additionally fuses head-mean + LN + ReLU + final 64->2 linear.
template <int LAYER>
__global__ __launch_bounds__(256)
void aggregate_kernel(const int* __restrict__ row_ptr, const int* __restrict__ col,
                      const bf16* __restrict__ hbuf,
                      const float* __restrict__ alpha_s, const float* __restrict__ alpha_d,
                      const bf16* __restrict__ resid,
                      const float* __restrict__ bias, const float* __restrict__ g,
                      const float* __restrict__ b,
                      const float* __restrict__ lw, const float* __restrict__ lb,
                      bf16* __restrict__ out_bf, float* __restrict__ out_f, int N) {
  int w = threadIdx.x >> 6;
  int lane = threadIdx.x & 63;
  int nn = blockIdx.x * 4 + w;
  bool valid = nn < N;
  int n = valid ? nn : 0;
  int h = lane >> 3;
  float adh = alpha_d[n * HEADS + h];
  float m = -1e30f, den = 0.f;
  float a[8] = {};
  int lo = row_ptr[n], hi = row_ptr[n + 1];

  for (int j = lo; j < hi; j += 8) {
    int idx[8]; float as[8]; uint4 u[8]; float e[8];
#pragma unroll
    for (int k = 0; k < 8; ++k) idx[k] = col[(j + k < hi) ? j + k : lo];
#pragma unroll
    for (int k = 0; k < 8; ++k) as[k] = alpha_s[idx[k] * HEADS + h];
#pragma unroll
    for (int k = 0; k < 8; ++k)
      u[k] = *reinterpret_cast<const uint4*>(hbuf + (size_t)idx[k] * HF + lane * 8);
#pragma unroll
    for (int k = 0; k < 8; ++k)
      e[k] = (j + k < hi) ? leaky(as[k] + adh) : -1e30f;
    float m01 = fmaxf(e[0], e[1]), m23 = fmaxf(e[2], e[3]);
    float m45 = fmaxf(e[4], e[5]), m67 = fmaxf(e[6], e[7]);
    float gmx = fmaxf(fmaxf(m01, m23), fmaxf(m45, m67));
    if (gmx > m) {                       // single rescale per group
      float sc = __expf(m - gmx);
      den *= sc;
#pragma unroll
      for (int i = 0; i < 8; ++i) a[i] *= sc;
      m = gmx;
    }
    float xk[8];
#pragma unroll
    for (int k = 0; k < 8; ++k) xk[k] = __expf(e[k] - m);   // invalid -> 0
#pragma unroll
    for (int k = 0; k < 8; ++k) den += xk[k];
#pragma unroll
    for (int k = 0; k < 8; ++k) {
      const unsigned short* pk = reinterpret_cast<const unsigned short*>(&u[k]);
#pragma unroll
      for (int i = 0; i < 8; ++i) a[i] = fmaf(xk[k], bits2f(pk[i]), a[i]);
    }
  }
  float inv = 1.f / den;
#pragma unroll
  for (int i = 0; i < 8; ++i) a[i] *= inv;

  if (LAYER < 2) {
    float4 b0 = ((const float4*)bias)[lane * 2];
    float4 b1 = ((const float4*)bias)[lane * 2 + 1];
    a[0] += b0.x; a[1] += b0.y; a[2] += b0.z; a[3] += b0.w;
    a[4] += b1.x; a[5] += b1.y; a[6] += b1.z; a[7] += b1.w;
    if (LAYER == 1) {
      uint4 rr = *reinterpret_cast<const uint4*>(resid + (size_t)n * HF + lane * 8);
      const unsigned short* rs = reinterpret_cast<const unsigned short*>(&rr);
#pragma unroll
      for (int i = 0; i < 8; ++i) a[i] += bits2f(rs[i]);
    }
    float s = 0.f, ss = 0.f;
#pragma unroll
    for (int i = 0; i < 8; ++i) { s += a[i]; ss += a[i] * a[i]; }
    s = wsum64(s); ss = wsum64(ss);
    float mu = s * (1.f / HF);
    float var = ss * (1.f / HF) - mu * mu;
    float rs = rsqrtf(var + LN_EPS);
    float4 g0 = ((const float4*)g)[lane * 2], g1 = ((const float4*)g)[lane * 2 + 1];
    float4 e0 = ((const float4*)b)[lane * 2], e1 = ((const float4*)b)[lane * 2 + 1];
    float gg[8] = {g0.x, g0.y, g0.z, g0.w, g1.x, g1.y, g1.z, g1.w};
    float be[8] = {e0.x, e0.y, e0.z, e0.w, e1.x, e1.y, e1.z, e1.w};
    unsigned short o[8];
#pragma unroll
    for (int i = 0; i < 8; ++i)
      o[i] = f2bits(fmaxf((a[i] - mu) * rs * gg[i] + be[i], 0.f));
    if (valid)
      *reinterpret_cast<uint4*>(out_bf + (size_t)n * HF + lane * 8) =
          *reinterpret_cast<const uint4*>(o);
  } else {
    // head mean via per-wave LDS slab (same-wave write->read, no barrier)
    __shared__ float lds[4][HF];
#pragma unroll
    for (int i = 0; i < 8; ++i) lds[w][lane * 8 + i] = a[i];
    float v = 0.f;
#pragma unroll
    for (int hh = 0; hh < HEADS; ++hh) v += lds[w][hh * HID + lane];
    v = v * (1.f / HEADS) + bias[lane];
    float s = wsum64(v);
    float ss = wsum64(v * v);
    float mu = s * (1.f / HID);
    float var = ss * (1.f / HID) - mu * mu;
    float rs = rsqrtf(var + LN_EPS);
    v = fmaxf((v - mu) * rs * g[lane] + b[lane], 0.f);
    // fused final linear: [64] @ [64,2] + lb
    float s0 = wsum64(v * lw[lane * 2 + 0]);
    float s1 = wsum64(v * lw[lane * 2 + 1]);
    if (valid && lane == 0) {
      out_f[(size_t)n * 2 + 0] = s0 + lb[0];
      out_f[(size_t)n * 2 + 1] = s1 + lb[1];
    }
  }
}

// ===========================================================================
extern "C" void kernel_launch(void* const* d_in, const int* in_sizes, int n_in,
                              void* d_out, int out_size, void* d_ws, size_t ws_size,
                              hipStream_t stream) {
  const float* x  = (const float*)d_in[0];
  const int*   ei = (const int*)d_in[1];
  const int N = in_sizes[0] / 165;       // 50000
  const int E = in_sizes[1] / 2;         // 400000
  const int Etot = E + N;
  const int K0P = 192;

  const float* W[3]  = {(const float*)d_in[2],  (const float*)d_in[8],  (const float*)d_in[14]};
  const float* As[3] = {(const float*)d_in[3],  (const float*)d_in[9],  (const float*)d_in[15]};
  const float* Ad[3] = {(const float*)d_in[4],  (const float*)d_in[10], (const float*)d_in[16]};
  const float* Bi[3] = {(const float*)d_in[5],  (const float*)d_in[11], (const float*)d_in[17]};
  const float* Lg[3] = {(const float*)d_in[6],  (const float*)d_in[12], (const float*)d_in[18]};
  const float* Lb[3] = {(const float*)d_in[7],  (const float*)d_in[13], (const float*)d_in[19]};
  const float* lin_w = (const float*)d_in[20];
  const float* lin_b = (const float*)d_in[21];

  // ---- workspace carve-up ----
  char* p = (char*)d_ws;
  auto alloc = [&](size_t bytes) {
    char* r = p;
    p += (bytes + 255) & ~(size_t)255;
    return r;
  };
  bf16* feat0   = (bf16*)alloc((size_t)N * HF * 2);   // layer outputs; aliases xbf
  bf16* hbuf    = (bf16*)alloc((size_t)N * HF * 2);
  float* alpha_s = (float*)alloc((size_t)N * HEADS * 4);
  float* alpha_d = (float*)alloc((size_t)N * HEADS * 4);
  bf16* W0t = (bf16*)alloc((size_t)HF * K0P * 2);
  bf16* W1t = (bf16*)alloc((size_t)HF * HF * 2);
  bf16* W2t = (bf16*)alloc((size_t)HF * HF * 2);
  int* esrc    = (int*)alloc((size_t)E * 4);
  int* edst    = (int*)alloc((size_t)E * 4);
  int* counts  = (int*)alloc((size_t)N * 4);
  int* row_ptr = (int*)alloc((size_t)(N + 1) * 4);
  int* cursor  = (int*)alloc((size_t)N * 4);
  int* col     = (int*)alloc((size_t)Etot * 4);
  int* bsum    = (int*)alloc((size_t)256 * 4);
  int* boff    = (int*)alloc((size_t)256 * 4);
  (void)ws_size;

  bf16* xbf = feat0;   // dead before aggregate<0> writes feat0

  const int NB = (N + SCAN_CHUNK - 1) / SCAN_CHUNK;   // 49 (<=64)

  // ---- edge normalize + CSR build ----
  hipMemsetAsync(counts, 0, (size_t)N * 4, stream);
  convert_count<<<(E + 255) / 256, 256, 0, stream>>>(ei, esrc, edst, counts, E);
  scan_pass1<<<NB, SCAN_T, 0, stream>>>(counts, bsum, N);
  scan_pass2<<<1, 64, 0, stream>>>(bsum, boff, NB);
  scan_pass3<<<NB, SCAN_T, 0, stream>>>(counts, boff, row_ptr, cursor, N, Etot);
  scatter_kernel<<<(Etot + 255) / 256, 256, 0, stream>>>(esrc, edst, cursor, col, N, E);

  // ---- merged prep ----
  {
    int total = N * K0P + HF * K0P + 2 * HF * HF;
    prep_kernel<<<(total + 255) / 256, 256, 0, stream>>>(
        x, xbf, W[0], W0t, W[1], W1t, W[2], W2t, N, K0P);
  }

  const int RT  = (N + 127) / 128;                 // 391 row tiles
  const int RTp = ((RT + 7) / 8) * 8;              // 392
  const int gemmBlocks = RTp * 4;                  // XCD-grouped 1D grid
  const int aggBlocks  = (N + 3) / 4;

  // ---- layer 0 ----
  gemm_mfma<<<gemmBlocks, 256, 0, stream>>>(xbf, W0t, hbuf, As[0], Ad[0],
                                            alpha_s, alpha_d, N, HF, K0P, RT);
  aggregate_kernel<0><<<aggBlocks, 256, 0, stream>>>(row_ptr, col, hbuf, alpha_s, alpha_d,
                                                     nullptr, Bi[0], Lg[0], Lb[0],
                                                     nullptr, nullptr, feat0, nullptr, N);

  // ---- layer 1 (in-place residual) ----
  gemm_mfma<<<gemmBlocks, 256, 0, stream>>>(feat0, W1t, hbuf, As[1], Ad[1],
                                            alpha_s, alpha_d, N, HF, HF, RT);
  aggregate_kernel<1><<<aggBlocks, 256, 0, stream>>>(row_ptr, col, hbuf, alpha_s, alpha_d,
                                                     feat0, Bi[1], Lg[1], Lb[1],
                                                     nullptr, nullptr, feat0, nullptr, N);

  // ---- layer 2 (head mean + LN + ReLU + final linear fused) ----
  gemm_mfma<<<gemmBlocks, 256, 0, stream>>>(feat0, W2t, hbuf, As[2], Ad[2],
                                            alpha_s, alpha_d, N, HF, HF, RT);
  aggregate_kernel<2><<<aggBlocks, 256, 0, stream>>>(row_ptr, col, hbuf, alpha_s, alpha_d,
                                                     nullptr, Bi[2], Lg[2], Lb[2],
                                                     lin_w, lin_b, nullptr, (float*)d_out, N);
}

// Round 10
// 431.215 us; speedup vs baseline: 1.1975x; 1.0095x over previous
//
#include <hip/hip_runtime.h>
#include <hip/hip_bf16.h>
#include <cstdint>
#include <cstddef>

#define HEADS 8
#define HID 64
#define HF 512              // HEADS*HID
#define NEG_SLOPE 0.2f
#define LN_EPS 1e-5f

typedef __hip_bfloat16 bf16;
typedef __attribute__((ext_vector_type(8))) __bf16 bf16v8;
typedef __attribute__((ext_vector_type(4))) float f32x4;

// ---------------- helpers ---------------------------------------------------
__device__ __forceinline__ float wsum64(float v) {
#pragma unroll
  for (int o = 32; o > 0; o >>= 1) v += __shfl_xor(v, o, 64);
  return v;
}
__device__ __forceinline__ int wsum64i(int v) {
#pragma unroll
  for (int o = 32; o > 0; o >>= 1) v += __shfl_xor(v, o, 64);
  return v;
}
__device__ __forceinline__ float leaky(float v) { return v >= 0.f ? v : NEG_SLOPE * v; }
__device__ __forceinline__ float bits2f(unsigned short u) {
  return __uint_as_float(((unsigned)u) << 16);
}
__device__ __forceinline__ unsigned short f2bits(float x) {
  union { bf16 h; unsigned short u; } bu;
  bu.h = __float2bfloat16(x);
  return bu.u;
}
// async global->LDS, 16B per lane (lds dest = wave-uniform base + lane*16)
__device__ __forceinline__ void gload_lds16(const bf16* src, short* lds_base) {
  __builtin_amdgcn_global_load_lds(
      (const __attribute__((address_space(1))) unsigned int*)src,
      (__attribute__((address_space(3))) unsigned int*)lds_base, 16, 0, 0);
}

// ---------------- edge normalize + count (handles int64 or int32) -----------
__global__ __launch_bounds__(256)
void convert_count(const int* __restrict__ ei, int* __restrict__ esrc,
                   int* __restrict__ edst, int* __restrict__ counts, int E) {
  int e = blockIdx.x * 256 + threadIdx.x;
  if (e >= E) return;
  bool i64 = (ei[1] == 0) && (ei[3] == 0) && (ei[5] == 0) && (ei[7] == 0);
  int s, d;
  if (i64) { s = ei[2 * (size_t)e]; d = ei[2 * ((size_t)E + e)]; }
  else     { s = ei[e];             d = ei[E + e]; }
  esrc[e] = s; edst[e] = d;
  atomicAdd(&counts[d], 1);
}

// ---------------- hierarchical exclusive scan over (counts[i]+1) ------------
#define SCAN_T 256
#define SCAN_EPT 4
#define SCAN_CHUNK (SCAN_T * SCAN_EPT)   // 1024

__global__ __launch_bounds__(SCAN_T)
void scan_pass1(const int* __restrict__ counts, int* __restrict__ bsum, int N) {
  int b = blockIdx.x, t = threadIdx.x;
  int base = b * SCAN_CHUNK + t * SCAN_EPT;
  int s = 0;
#pragma unroll
  for (int i = 0; i < SCAN_EPT; ++i) {
    int idx = base + i;
    if (idx < N) s += counts[idx] + 1;
  }
  int lane = t & 63, w = t >> 6;
  int tot = wsum64i(s);
  __shared__ int ws[4];
  if (lane == 0) ws[w] = tot;
  __syncthreads();
  if (t == 0) bsum[b] = ws[0] + ws[1] + ws[2] + ws[3];
}

__global__ __launch_bounds__(64)
void scan_pass2(const int* __restrict__ bsum, int* __restrict__ boff, int NB) {
  int t = threadIdx.x;
  int own = t < NB ? bsum[t] : 0;
  int v = own;
#pragma unroll
  for (int o = 1; o < 64; o <<= 1) {
    int u = __shfl_up(v, o, 64);
    if (t >= o) v += u;
  }
  if (t < NB) boff[t] = v - own;   // exclusive
}

__global__ __launch_bounds__(SCAN_T)
void scan_pass3(const int* __restrict__ counts, const int* __restrict__ boff,
                int* __restrict__ row_ptr, int* __restrict__ cursor, int N, int Etot) {
  int b = blockIdx.x, t = threadIdx.x;
  int base = b * SCAN_CHUNK + t * SCAN_EPT;
  int c[SCAN_EPT];
  int s = 0;
#pragma unroll
  for (int i = 0; i < SCAN_EPT; ++i) {
    int idx = base + i;
    c[i] = idx < N ? counts[idx] + 1 : 0;
    s += c[i];
  }
  int lane = t & 63, w = t >> 6;
  int inc = s;
#pragma unroll
  for (int o = 1; o < 64; o <<= 1) {
    int u = __shfl_up(inc, o, 64);
    if (lane >= o) inc += u;
  }
  __shared__ int wsums[4];
  if (lane == 63) wsums[w] = inc;
  __syncthreads();
  int woff = 0;
  for (int i = 0; i < w; ++i) woff += wsums[i];
  int run = inc - s + woff + boff[b];
#pragma unroll
  for (int i = 0; i < SCAN_EPT; ++i) {
    int idx = base + i;
    if (idx < N) { row_ptr[idx] = run; cursor[idx] = run; run += c[i]; }
  }
  if (b == 0 && t == 0) row_ptr[N] = Etot;
}

__global__ __launch_bounds__(256)
void scatter_kernel(const int* __restrict__ esrc, const int* __restrict__ edst,
                    int* __restrict__ cursor, int* __restrict__ col, int N, int E) {
  int e = blockIdx.x * 256 + threadIdx.x;
  int Etot = E + N;
  if (e >= Etot) return;
  int s = e < E ? esrc[e] : e - E;
  int d = e < E ? edst[e] : e - E;
  int pos = atomicAdd(&cursor[d], 1);
  col[pos] = s;
}

// ---------------- merged prep: x->bf16 pad + 3x W->W^T bf16 -----------------
__global__ __launch_bounds__(256)
void prep_kernel(const float* __restrict__ x, bf16* __restrict__ xbf,
                 const float* __restrict__ W0, bf16* __restrict__ W0t,
                 const float* __restrict__ W1, bf16* __restrict__ W1t,
                 const float* __restrict__ W2, bf16* __restrict__ W2t,
                 int N, int K0P) {
  const int S0 = N * K0P;            // xbf
  const int S1 = HF * K0P;           // W0t
  const int S2 = HF * HF;            // W1t / W2t
  int idx = blockIdx.x * 256 + threadIdx.x;
  if (idx < S0) {
    int row = idx / K0P, colk = idx - row * K0P;
    float v = colk < 165 ? x[(size_t)row * 165 + colk] : 0.f;
    xbf[idx] = __float2bfloat16(v);
    return;
  }
  idx -= S0;
  if (idx < S1) {
    int n = idx / K0P, k = idx - n * K0P;
    float v = k < 165 ? W0[(size_t)k * HF + n] : 0.f;
    W0t[idx] = __float2bfloat16(v);
    return;
  }
  idx -= S1;
  if (idx < S2) {
    int n = idx >> 9, k = idx & 511;
    W1t[idx] = __float2bfloat16(W1[(size_t)k * HF + n]);
    return;
  }
  idx -= S2;
  if (idx < S2) {
    int n = idx >> 9, k = idx & 511;
    W2t[idx] = __float2bfloat16(W2[(size_t)k * HF + n]);
  }
}

// ---------------- MFMA GEMM + fused alpha epilogue ---------------------------
// C[M,512] = A[M,K](bf16) @ Bt[512,K](bf16)^T ; alpha_s/d[M,8] = h . a
// XCD-grouped 1D grid + double-buffered staging with COUNTED vmcnt (T4):
// raw s_barrier + s_waitcnt vmcnt(4); prefetch spans barriers, never drains.
__global__ __launch_bounds__(256)
void gemm_mfma(const bf16* __restrict__ A, const bf16* __restrict__ Bt,
               bf16* __restrict__ C,
               const float* __restrict__ as_g, const float* __restrict__ ad_g,
               float* __restrict__ alpha_s, float* __restrict__ alpha_d,
               int M, int Ncols, int K, int RT) {
  const int id = blockIdx.x;
  const int xcd = id & 7;
  const int q = id >> 3;
  const int cco = q & 3;
  const int rt = (q >> 2) * 8 + xcd;
  if (rt >= RT) return;                   // uniform across block
  const int row0 = rt * 128, col0 = cco * 128;

  __shared__ short Alds[2][128 * 32];
  __shared__ short Blds[2][128 * 32];
  const int tid = threadIdx.x;
  const int wave = tid >> 6, lane = tid & 63;
  const int wr = wave >> 1, wc = wave & 1;
  const int lrow = lane & 15;
  const int kc = lane >> 4;
  const int sr = lane >> 2, sc4 = lane & 3;   // staging: 4 lanes/row
  f32x4 acc[4][4] = {};

  // staging: one 128x32 bf16 tile of A and Bt into buffer pb at k-offset k0
  // 4 gload_lds per wave per call (vmcnt += 4)
  auto stage = [&](int k0, int pb) {
#pragma unroll
    for (int i = 0; i < 2; ++i) {
      int rbase = (wave + i * 4) * 16;       // 16 rows per wave-issue
      int r = rbase + sr;
      int slot = sc4 ^ ((r >> 1) & 3);       // inverse-swizzled global source
      int gm = row0 + r; if (gm >= M) gm = M - 1;
      gload_lds16(A + (size_t)gm * K + k0 + slot * 8, &Alds[pb][rbase * 32]);
      gload_lds16(Bt + (size_t)(col0 + r) * K + k0 + slot * 8, &Blds[pb][rbase * 32]);
    }
  };

  const int nk = K >> 5;
  stage(0, 0);                               // 4 outstanding
  stage(32, 1);                              // 8 outstanding
  asm volatile("s_waitcnt vmcnt(4)" ::: "memory");   // tile 0 landed
  __builtin_amdgcn_s_barrier();
  int p = 0;
  for (int k = 0; k < nk; ++k) {
    bf16v8 af[4], bfr[4];
#pragma unroll
    for (int r = 0; r < 4; ++r) {
      int row = wr * 64 + r * 16 + lrow;
      af[r] = *reinterpret_cast<const bf16v8*>(
          &Alds[p][row * 32 + ((kc ^ ((row >> 1) & 3)) << 3)]);
    }
#pragma unroll
    for (int c = 0; c < 4; ++c) {
      int row = wc * 64 + c * 16 + lrow;
      bfr[c] = *reinterpret_cast<const bf16v8*>(
          &Blds[p][row * 32 + ((kc ^ ((row >> 1) & 3)) << 3)]);
    }
#pragma unroll
    for (int r = 0; r < 4; ++r)
#pragma unroll
      for (int c = 0; c < 4; ++c)
        acc[r][c] = __builtin_amdgcn_mfma_f32_16x16x32_bf16(af[r], bfr[c], acc[r][c], 0, 0, 0);
    if (k + 1 == nk) break;                  // last tile computed: done
    __builtin_amdgcn_s_barrier();            // all waves finished reading buf p
    if (k + 2 < nk) {
      stage((k + 2) << 5, p);                // overwrite p (safe: post-barrier)
      asm volatile("s_waitcnt vmcnt(4)" ::: "memory");  // tile k+1 landed
    } else {
      asm volatile("s_waitcnt vmcnt(0)" ::: "memory");  // final tile landed
    }
    __builtin_amdgcn_s_barrier();            // all waves' tile k+1 visible
    p ^= 1;
  }

  // C write: C/D layout col=lane&15, row=(lane>>4)*4+j  [m89]
  const int crow = (lane >> 4) * 4;
  const int ccol = lane & 15;
#pragma unroll
  for (int r = 0; r < 4; ++r) {
#pragma unroll
    for (int c = 0; c < 4; ++c) {
      int gc = col0 + wc * 64 + c * 16 + ccol;
#pragma unroll
      for (int j = 0; j < 4; ++j) {
        int gr = row0 + wr * 64 + r * 16 + crow + j;
        if (gr < M) C[(size_t)gr * Ncols + gc] = __float2bfloat16(acc[r][c][j]);
      }
    }
  }

  // fused alpha epilogue: this wave's 64 cols = head (col0+wc*64)>>6
  const int head = (col0 + wc * 64) >> 6;
  float asf[4], adf[4];
#pragma unroll
  for (int c = 0; c < 4; ++c) {
    asf[c] = as_g[head * HID + c * 16 + ccol];
    adf[c] = ad_g[head * HID + c * 16 + ccol];
  }
#pragma unroll
  for (int r = 0; r < 4; ++r) {
#pragma unroll
    for (int j = 0; j < 4; ++j) {
      float ps = 0.f, pd = 0.f;
#pragma unroll
      for (int c = 0; c < 4; ++c) {
        ps = fmaf(acc[r][c][j], asf[c], ps);
        pd = fmaf(acc[r][c][j], adf[c], pd);
      }
#pragma unroll
      for (int o = 1; o < 16; o <<= 1) {
        ps += __shfl_xor(ps, o, 64);
        pd += __shfl_xor(pd, o, 64);
      }
      if (ccol == 0) {
        int gr = row0 + wr * 64 + r * 16 + crow + j;
        if (gr < M) {
          alpha_s[gr * HEADS + head] = ps;
          alpha_d[gr * HEADS + head] = pd;
        }
      }
    }
  }
}

// ---------------- fused aggregate (online softmax, 8-edge groups) -----------
// ONE WAVE per node: lane owns 8 features, head = lane>>3. 4 nodes / block.
// LAYER 2 additionally fuses head-mean + LN + ReLU + final 64->2 linear.
template <int LAYER>
__global__ __launch_bounds__(256)
void aggregate_kernel(const int* __restrict__ row_ptr, const int* __restrict__ col,
                      const bf16* __restrict__ hbuf,
                      const float* __restrict__ alpha_s, const float* __restrict__ alpha_d,
                      const bf16* __restrict__ resid,
                      const float* __restrict__ bias, const float* __restrict__ g,
                      const float* __restrict__ b,
                      const float* __restrict__ lw, const float* __restrict__ lb,
                      bf16* __restrict__ out_bf, float* __restrict__ out_f, int N) {
  int w = threadIdx.x >> 6;
  int lane = threadIdx.x & 63;
  int nn = blockIdx.x * 4 + w;
  bool valid = nn < N;
  int n = valid ? nn : 0;
  int h = lane >> 3;
  float adh = alpha_d[n * HEADS + h];
  float m = -1e30f, den = 0.f;
  float a[8] = {};
  int lo = row_ptr[n], hi = row_ptr[n + 1];

  for (int j = lo; j < hi; j += 8) {
    int idx[8]; float as[8]; uint4 u[8]; float e[8];
#pragma unroll
    for (int k = 0; k < 8; ++k) idx[k] = col[(j + k < hi) ? j + k : lo];
#pragma unroll
    for (int k = 0; k < 8; ++k) as[k] = alpha_s[idx[k] * HEADS + h];
#pragma unroll
    for (int k = 0; k < 8; ++k)
      u[k] = *reinterpret_cast<const uint4*>(hbuf + (size_t)idx[k] * HF + lane * 8);
#pragma unroll
    for (int k = 0; k < 8; ++k)
      e[k] = (j + k < hi) ? leaky(as[k] + adh) : -1e30f;
    float m01 = fmaxf(e[0], e[1]), m23 = fmaxf(e[2], e[3]);
    float m45 = fmaxf(e[4], e[5]), m67 = fmaxf(e[6], e[7]);
    float gmx = fmaxf(fmaxf(m01, m23), fmaxf(m45, m67));
    if (gmx > m) {                       // single rescale per group
      float sc = __expf(m - gmx);
      den *= sc;
#pragma unroll
      for (int i = 0; i < 8; ++i) a[i] *= sc;
      m = gmx;
    }
    float xk[8];
#pragma unroll
    for (int k = 0; k < 8; ++k) xk[k] = __expf(e[k] - m);   // invalid -> 0
#pragma unroll
    for (int k = 0; k < 8; ++k) den += xk[k];
#pragma unroll
    for (int k = 0; k < 8; ++k) {
      const unsigned short* pk = reinterpret_cast<const unsigned short*>(&u[k]);
#pragma unroll
      for (int i = 0; i < 8; ++i) a[i] = fmaf(xk[k], bits2f(pk[i]), a[i]);
    }
  }
  float inv = 1.f / den;
#pragma unroll
  for (int i = 0; i < 8; ++i) a[i] *= inv;

  if (LAYER < 2) {
    float4 b0 = ((const float4*)bias)[lane * 2];
    float4 b1 = ((const float4*)bias)[lane * 2 + 1];
    a[0] += b0.x; a[1] += b0.y; a[2] += b0.z; a[3] += b0.w;
    a[4] += b1.x; a[5] += b1.y; a[6] += b1.z; a[7] += b1.w;
    if (LAYER == 1) {
      uint4 rr = *reinterpret_cast<const uint4*>(resid + (size_t)n * HF + lane * 8);
      const unsigned short* rs = reinterpret_cast<const unsigned short*>(&rr);
#pragma unroll
      for (int i = 0; i < 8; ++i) a[i] += bits2f(rs[i]);
    }
    float s = 0.f, ss = 0.f;
#pragma unroll
    for (int i = 0; i < 8; ++i) { s += a[i]; ss += a[i] * a[i]; }
    s = wsum64(s); ss = wsum64(ss);
    float mu = s * (1.f / HF);
    float var = ss * (1.f / HF) - mu * mu;
    float rs = rsqrtf(var + LN_EPS);
    float4 g0 = ((const float4*)g)[lane * 2], g1 = ((const float4*)g)[lane * 2 + 1];
    float4 e0 = ((const float4*)b)[lane * 2], e1 = ((const float4*)b)[lane * 2 + 1];
    float gg[8] = {g0.x, g0.y, g0.z, g0.w, g1.x, g1.y, g1.z, g1.w};
    float be[8] = {e0.x, e0.y, e0.z, e0.w, e1.x, e1.y, e1.z, e1.w};
    unsigned short o[8];
#pragma unroll
    for (int i = 0; i < 8; ++i)
      o[i] = f2bits(fmaxf((a[i] - mu) * rs * gg[i] + be[i], 0.f));
    if (valid)
      *reinterpret_cast<uint4*>(out_bf + (size_t)n * HF + lane * 8) =
          *reinterpret_cast<const uint4*>(o);
  } else {
    // head mean via per-wave LDS slab (same-wave write->read, no barrier)
    __shared__ float lds[4][HF];
#pragma unroll
    for (int i = 0; i < 8; ++i) lds[w][lane * 8 + i] = a[i];
    float v = 0.f;
#pragma unroll
    for (int hh = 0; hh < HEADS; ++hh) v += lds[w][hh * HID + lane];
    v = v * (1.f / HEADS) + bias[lane];
    float s = wsum64(v);
    float ss = wsum64(v * v);
    float mu = s * (1.f / HID);
    float var = ss * (1.f / HID) - mu * mu;
    float rs = rsqrtf(var + LN_EPS);
    v = fmaxf((v - mu) * rs * g[lane] + b[lane], 0.f);
    // fused final linear: [64] @ [64,2] + lb
    float s0 = wsum64(v * lw[lane * 2 + 0]);
    float s1 = wsum64(v * lw[lane * 2 + 1]);
    if (valid && lane == 0) {
      out_f[(size_t)n * 2 + 0] = s0 + lb[0];
      out_f[(size_t)n * 2 + 1] = s1 + lb[1];
    }
  }
}

// ===========================================================================
extern "C" void kernel_launch(void* const* d_in, const int* in_sizes, int n_in,
                              void* d_out, int out_size, void* d_ws, size_t ws_size,
                              hipStream_t stream) {
  const float* x  = (const float*)d_in[0];
  const int*   ei = (const int*)d_in[1];
  const int N = in_sizes[0] / 165;       // 50000
  const int E = in_sizes[1] / 2;         // 400000
  const int Etot = E + N;
  const int K0P = 192;

  const float* W[3]  = {(const float*)d_in[2],  (const float*)d_in[8],  (const float*)d_in[14]};
  const float* As[3] = {(const float*)d_in[3],  (const float*)d_in[9],  (const float*)d_in[15]};
  const float* Ad[3] = {(const float*)d_in[4],  (const float*)d_in[10], (const float*)d_in[16]};
  const float* Bi[3] = {(const float*)d_in[5],  (const float*)d_in[11], (const float*)d_in[17]};
  const float* Lg[3] = {(const float*)d_in[6],  (const float*)d_in[12], (const float*)d_in[18]};
  const float* Lb[3] = {(const float*)d_in[7],  (const float*)d_in[13], (const float*)d_in[19]};
  const float* lin_w = (const float*)d_in[20];
  const float* lin_b = (const float*)d_in[21];

  // ---- workspace carve-up ----
  char* p = (char*)d_ws;
  auto alloc = [&](size_t bytes) {
    char* r = p;
    p += (bytes + 255) & ~(size_t)255;
    return r;
  };
  bf16* feat0   = (bf16*)alloc((size_t)N * HF * 2);   // layer outputs; aliases xbf
  bf16* hbuf    = (bf16*)alloc((size_t)N * HF * 2);
  float* alpha_s = (float*)alloc((size_t)N * HEADS * 4);
  float* alpha_d = (float*)alloc((size_t)N * HEADS * 4);
  bf16* W0t = (bf16*)alloc((size_t)HF * K0P * 2);
  bf16* W1t = (bf16*)alloc((size_t)HF * HF * 2);
  bf16* W2t = (bf16*)alloc((size_t)HF * HF * 2);
  int* esrc    = (int*)alloc((size_t)E * 4);
  int* edst    = (int*)alloc((size_t)E * 4);
  int* counts  = (int*)alloc((size_t)N * 4);
  int* row_ptr = (int*)alloc((size_t)(N + 1) * 4);
  int* cursor  = (int*)alloc((size_t)N * 4);
  int* col     = (int*)alloc((size_t)Etot * 4);
  int* bsum    = (int*)alloc((size_t)256 * 4);
  int* boff    = (int*)alloc((size_t)256 * 4);
  (void)ws_size;

  bf16* xbf = feat0;   // dead before aggregate<0> writes feat0

  const int NB = (N + SCAN_CHUNK - 1) / SCAN_CHUNK;   // 49 (<=64)

  // ---- edge normalize + CSR build ----
  hipMemsetAsync(counts, 0, (size_t)N * 4, stream);
  convert_count<<<(E + 255) / 256, 256, 0, stream>>>(ei, esrc, edst, counts, E);
  scan_pass1<<<NB, SCAN_T, 0, stream>>>(counts, bsum, N);
  scan_pass2<<<1, 64, 0, stream>>>(bsum, boff, NB);
  scan_pass3<<<NB, SCAN_T, 0, stream>>>(counts, boff, row_ptr, cursor, N, Etot);
  scatter_kernel<<<(Etot + 255) / 256, 256, 0, stream>>>(esrc, edst, cursor, col, N, E);

  // ---- merged prep ----
  {
    int total = N * K0P + HF * K0P + 2 * HF * HF;
    prep_kernel<<<(total + 255) / 256, 256, 0, stream>>>(
        x, xbf, W[0], W0t, W[1], W1t, W[2], W2t, N, K0P);
  }

  const int RT  = (N + 127) / 128;                 // 391 row tiles
  const int RTp = ((RT + 7) / 8) * 8;              // 392
  const int gemmBlocks = RTp * 4;                  // XCD-grouped 1D grid
  const int aggBlocks  = (N + 3) / 4;

  // ---- layer 0 ----
  gemm_mfma<<<gemmBlocks, 256, 0, stream>>>(xbf, W0t, hbuf, As[0], Ad[0],
                                            alpha_s, alpha_d, N, HF, K0P, RT);
  aggregate_kernel<0><<<aggBlocks, 256, 0, stream>>>(row_ptr, col, hbuf, alpha_s, alpha_d,
                                                     nullptr, Bi[0], Lg[0], Lb[0],
                                                     nullptr, nullptr, feat0, nullptr, N);

  // ---- layer 1 (in-place residual) ----
  gemm_mfma<<<gemmBlocks, 256, 0, stream>>>(feat0, W1t, hbuf, As[1], Ad[1],
                                            alpha_s, alpha_d, N, HF, HF, RT);
  aggregate_kernel<1><<<aggBlocks, 256, 0, stream>>>(row_ptr, col, hbuf, alpha_s, alpha_d,
                                                     feat0, Bi[1], Lg[1], Lb[1],
                                                     nullptr, nullptr, feat0, nullptr, N);

  // ---- layer 2 (head mean + LN + ReLU + final linear fused) ----
  gemm_mfma<<<gemmBlocks, 256, 0, stream>>>(feat0, W2t, hbuf, As[2], Ad[2],
                                            alpha_s, alpha_d, N, HF, HF, RT);
  aggregate_kernel<2><<<aggBlocks, 256, 0, stream>>>(row_ptr, col, hbuf, alpha_s, alpha_d,
                                                     nullptr, Bi[2], Lg[2], Lb[2],
                                                     lin_w, lin_b, nullptr, (float*)d_out, N);
}